// Round 20
// baseline (249.456 us; speedup 1.0000x reference)
//
#include <hip/hip_runtime.h>
#include <hip/hip_bf16.h>
#include <math.h>

#define BATCH   32
#define A_TOTAL 8400
#define NCLS    80

typedef __attribute__((ext_vector_type(8))) short bf16x8;
typedef __attribute__((ext_vector_type(4))) float f32x4;

__device__ __forceinline__ short f2bf(float f) {
    union { float f; unsigned u; } v; v.f = f;
    unsigned u = v.u + 0x7fffu + ((v.u >> 16) & 1u);   // round-nearest-even
    return (short)(u >> 16);
}

// fast sigmoid: v_exp_f32 + v_rcp_f32 (error ~2^-21, way under bf16-conv noise)
__device__ __forceinline__ float fsig(float x) {
    return __builtin_amdgcn_rcpf(1.f + __expf(-x));
}

// async global->LDS, 16B per lane; lds dest = wave-uniform base + lane*16
__device__ __forceinline__ void stage16(const void* g, void* ldsp) {
    __builtin_amdgcn_global_load_lds(
        (const __attribute__((address_space(1))) unsigned int*)g,
        (__attribute__((address_space(3))) unsigned int*)ldsp, 16, 0, 0);
}

// DPP pixel shifts within 16-lane rows (frag = 16 consecutive pixels/lane).
__device__ __forceinline__ bf16x8 shp1(bf16x8 cur, bf16x8 nxt) {   // pixel +1
    union { bf16x8 v; int d[4]; } c{cur}, n{nxt}, r;
#pragma unroll
    for (int i = 0; i < 4; ++i) {
        int t = __builtin_amdgcn_update_dpp(0, n.d[i], 0x11F, 0xF, 0xF, false);
        r.d[i] = __builtin_amdgcn_update_dpp(t, c.d[i], 0x101, 0xF, 0xF, false);
    }
    return r.v;
}
__device__ __forceinline__ bf16x8 shm1(bf16x8 cur, bf16x8 prv) {   // pixel -1
    union { bf16x8 v; int d[4]; } c{cur}, p{prv}, r;
#pragma unroll
    for (int i = 0; i < 4; ++i) {
        int t = __builtin_amdgcn_update_dpp(0, p.d[i], 0x10F, 0xF, 0xF, false);
        r.d[i] = __builtin_amdgcn_update_dpp(t, c.d[i], 0x111, 0xF, 0xF, false);
    }
    return r.v;
}

// ---------------------------------------------------------------------------
// Weight prep (all 3 levels in ONE launch):
// Afrag[tap][kc][mf(10)][lane(64)][8] bf16, M padded 148->160.
// ---------------------------------------------------------------------------
__device__ __forceinline__ void prep_w_body(const float* wc, const float* wr,
                                            __hip_bfloat16* af, int C, int bidl) {
    const int KC = C / 32;
    const int total = 9 * KC * 10 * 64;
    int idx = bidl * 256 + threadIdx.x;
    if (idx >= total) return;
    int l   = idx & 63;
    int rem = idx >> 6;
    int mf  = rem % 10;
    int kc  = (rem / 10) % KC;
    int tap = rem / (10 * KC);
    int m     = mf * 16 + (l & 15);
    int cbase = kc * 32 + (l >> 4) * 8;
    short v[8];
#pragma unroll
    for (int j = 0; j < 8; ++j) {
        int c = cbase + j;
        float w = 0.f;
        if (m < 80)        w = wc[((size_t)m * C + c) * 9 + tap];
        else if (m < 148)  w = wr[((size_t)(m - 80) * C + c) * 9 + tap];
        v[j] = f2bf(w);
    }
    *(bf16x8*)((short*)af + (size_t)idx * 8) = *(bf16x8*)v;
}

__global__ __launch_bounds__(256) void prep_w_all(
    const float* __restrict__ wc0, const float* __restrict__ wr0,
    const float* __restrict__ wc1, const float* __restrict__ wr1,
    const float* __restrict__ wc2, const float* __restrict__ wr2,
    __hip_bfloat16* __restrict__ af0, __hip_bfloat16* __restrict__ af1,
    __hip_bfloat16* __restrict__ af2) {
    int b = blockIdx.x;
    if (b < 90)       prep_w_body(wc0, wr0, af0, 128, b);
    else if (b < 270) prep_w_body(wc1, wr1, af1, 256, b - 90);
    else              prep_w_body(wc2, wr2, af2, 512, b - 270);
}

// ---------------------------------------------------------------------------
// NCHW fp32 -> zero-padded xT[n][kc][j(4)][(H+2)(W+2)][8 bf16].
// ---------------------------------------------------------------------------
template<int C, int H, int W>
__global__ __launch_bounds__(256) void transpose_x(const float* __restrict__ x,
                                                   __hip_bfloat16* __restrict__ xT) {
    const int CC  = C / 64;
    const int KC  = C / 32;
    const int PW  = W + 2;
    const int PHW = (H + 2) * PW;
    int b   = blockIdx.x;
    int cch = b % CC;
    int y   = (b / CC) % H;
    int n   = b / (CC * H);
    __shared__ float sm[64][W + 1];
    const float* src = x + (((size_t)n * C + cch * 64) * H + y) * W;
    for (int i = threadIdx.x; i < 64 * (W / 4); i += 256) {
        int c = i / (W / 4), f4 = i % (W / 4);
        float4 v = *(const float4*)(src + (size_t)c * H * W + f4 * 4);
        sm[c][f4 * 4 + 0] = v.x;
        sm[c][f4 * 4 + 1] = v.y;
        sm[c][f4 * 4 + 2] = v.z;
        sm[c][f4 * 4 + 3] = v.w;
    }
    __syncthreads();
    short* base = (short*)xT + (size_t)n * KC * 4 * PHW * 8;
    for (int u = threadIdx.x; u < W * 8; u += 256) {
        int g8 = u / W, xc = u % W;
        int kc = cch * 2 + (g8 >> 2);
        int j  = g8 & 3;
        short v[8];
#pragma unroll
        for (int jj = 0; jj < 8; ++jj) v[jj] = f2bf(sm[g8 * 8 + jj][xc]);
        *(bf16x8*)(base + (((size_t)(kc * 4 + j)) * PHW + (y + 1) * PW + xc + 1) * 8) =
            *(bf16x8*)v;
    }
    bf16x8 z = (bf16x8)(short)0;
    if (threadIdx.x < 16) {
        int g8 = threadIdx.x >> 1, side = threadIdx.x & 1;
        int kc = cch * 2 + (g8 >> 2), j = g8 & 3;
        *(bf16x8*)(base + (((size_t)(kc * 4 + j)) * PHW + (y + 1) * PW + side * (W + 1)) * 8) = z;
    }
    if (y == 0) {
        for (int u = threadIdx.x; u < PW * 8; u += 256) {
            int g8 = u / PW, col = u % PW;
            int kc = cch * 2 + (g8 >> 2), j = g8 & 3;
            *(bf16x8*)(base + (((size_t)(kc * 4 + j)) * PHW + col) * 8) = z;
        }
    }
    if (y == H - 1) {
        for (int u = threadIdx.x; u < PW * 8; u += 256) {
            int g8 = u / PW, col = u % PW;
            int kc = cch * 2 + (g8 >> 2), j = g8 & 3;
            *(bf16x8*)(base + (((size_t)(kc * 4 + j)) * PHW + (H + 1) * PW + col) * 8) = z;
        }
    }
}

// ---------------------------------------------------------------------------
// Implicit-GEMM head on zero-padded image.
// DPPB==0: flat-window LDS B, 9 taps, per-tap ds_reads (L1/L2 path).
// DPPB==1 (L0): row-aligned NT=160 tile (2 rows, NF=5, WEU=2); B staged as 4
//   padded rows; per dy read 7 frags, dx=+-1 via DPP lane shifts; A prefetch
//   depth 2 (a0/a1/a2) — regs fit the WEU=2 budget (~240 <= 256).
// ---------------------------------------------------------------------------
template<int C, int H, int W, int STRIDE, int A_OFFp, int LVL, int NT, int KS,
         int NTHR, int WEU, int DPPB>
__global__ __launch_bounds__(NTHR, WEU) void gemm_head(
    const __hip_bfloat16* __restrict__ xT,
    const __hip_bfloat16* __restrict__ af,
    const float* __restrict__ bc, const float* __restrict__ br,
    const float* __restrict__ scales,
    float* __restrict__ out_cls, float* __restrict__ out_box,
    float* __restrict__ pbuf) {
    constexpr int HW     = H * W;
    constexpr int PW     = W + 2;
    constexpr int PHW    = (H + 2) * PW;
    constexpr int WAVES  = NTHR / 64;
    constexpr int WN     = WAVES / 2;
    constexpr int NF     = NT / (16 * WN);
    static_assert(NT == WN * NF * 16, "NT must equal WN*NF*16");
    static_assert(!DPPB || (NF == 5 && W == 80 && NT == 160 && NTHR == 256 && KS == 1),
                  "DPP path assumes 2-row 160px tile");
    constexpr int TILES  = (HW + NT - 1) / NT;
    constexpr int KC     = C / 32;
    constexpr int KCS    = KC / KS;
    constexpr int DYMAX  = (NT - 1) / W + 1;
    constexpr int NSTAGE = NT + 2 * DYMAX + 2 * W + 7;
    constexpr int NS16   = NSTAGE * 16;
    constexpr int NG     = NSTAGE * 4;
    constexpr int ITBv   = DPPB ? 9 : ((NG + NTHR - 1) / NTHR);
    constexpr int BSZ    = DPPB ? (9 * NTHR * 16) : (ITBv * NTHR * 16);
    constexpr int EPI    = 68 * (NT + 4) * 4;
    constexpr int LDSB   = (KS > 1) ? (2 * BSZ) : ((2 * BSZ) > EPI ? (2 * BSZ) : EPI);
    static_assert(ITBv <= 9, "B staging spread exceeds tap steps");

    __shared__ __align__(16) char lds[LDSB];

    constexpr int NWG = BATCH * TILES * KS;
    const int bid  = blockIdx.x;
    const int swz  = (bid & 7) * (NWG / 8) + (bid >> 3);
    const int ks   = swz % KS;
    const int rest = swz / KS;
    const int tile = rest % TILES;
    const int n    = rest / TILES;

    const int tid   = threadIdx.x;
    const int l     = tid & 63;
    const int wid   = __builtin_amdgcn_readfirstlane(tid >> 6);
    const int mhalf = wid & 1;
    const int ng    = wid >> 1;      // n-group (DPPB: output image row within tile)
    const int lr    = l & 15;
    const int kg    = l >> 4;

    const char* xb  = (const char*)xT + (size_t)n * KC * 4 * PHW * 16;
    const char* afc = (const char*)af;

    const int p0    = tile * NT;

    int blane[NF];
    unsigned bsoff[ITBv];
    int base2 = 0;
    if constexpr (DPPB) {
        base2 = (kg * 515 + lr + 1) * 16;
#pragma unroll
        for (int it = 0; it < ITBv; ++it) {
            int idx = it * NTHR + tid; if (idx > 2059) idx = 2059;
            int j = idx / 515;
            int rem = idx - j * 515; if (rem > 511) rem = 511;
            int g = rem >> 7, px = rem & 127;
            int pos = px - 16; pos = pos < 0 ? 0 : (pos > W + 1 ? W + 1 : pos);
            int q = (2 * tile + g) * PW + pos;
            bsoff[it] = (unsigned)((j * PHW + q) * 16);
        }
    } else {
        const int qbase = (p0 / W) * PW + (p0 % W);
#pragma unroll
        for (int nf = 0; nf < NF; ++nf) {
            int p  = p0 + (ng * NF + nf) * 16 + lr;
            int qc = (p / W + 1) * PW + (p % W) + 1;
            blane[nf] = kg * NS16 + (qc - (W + 3) - qbase) * 16;
        }
#pragma unroll
        for (int it = 0; it < ITBv; ++it) {
            int idx = it * NTHR + tid;
            int j = idx / NSTAGE; if (j > 3) j = 3;
            int q = qbase + (idx - j * NSTAGE);
            if (q > PHW - 1) q = PHW - 1;
            bsoff[it] = (unsigned)((j * PHW + q) * 16);
        }
    }

    f32x4 acc[5][NF];
#pragma unroll
    for (int mf = 0; mf < 5; ++mf)
#pragma unroll
        for (int nf = 0; nf < NF; ++nf) acc[mf][nf] = (f32x4)0.f;

    auto stageB = [&](int it, int kc, unsigned dstbase) {
        stage16(xb + (size_t)kc * (4 * PHW * 16) + bsoff[it],
                &lds[dstbase + it * (NTHR * 16) + wid * 1024]);
    };
    auto loadA = [&](bf16x8* dst, int step) {
        const char* asrc = afc + (size_t)step * 10240 + mhalf * 5120 + l * 16;
#pragma unroll
        for (int mf = 0; mf < 5; ++mf)
            dst[mf] = *(const bf16x8*)(asrc + mf * 1024);
    };

    const int kc0 = ks * KCS;

    unsigned curB = 0;

    if constexpr (DPPB) {
        // A register pipeline depth 2 (rule #20: only static names, full unroll)
        bf16x8 a0[5], a1[5], a2[5];
        loadA(a0, kc0);            // (tap0, kc0)
        loadA(a1, KC + kc0);       // (tap1, kc0)
#pragma unroll
        for (int it = 0; it < ITBv; ++it) stageB(it, kc0, 0);
        __syncthreads();

        auto doTap = [&](int tap, int kc, bf16x8 b0, bf16x8 b1, bf16x8 b2,
                         bf16x8 b3, bf16x8 b4) {
            // prefetch step tap+2 (tail over-reads stay inside af)
            const int nstep2 = (tap <= 6) ? ((tap + 2) * KC + kc)
                             : (tap == 7) ? (kc + 1)
                                          : (KC + kc + 1);
            loadA(a2, nstep2);
            bf16x8 bv[5] = {b0, b1, b2, b3, b4};
            __builtin_amdgcn_s_setprio(1);
#pragma unroll
            for (int nf = 0; nf < 5; ++nf)
#pragma unroll
                for (int mf = 0; mf < 5; ++mf)
                    acc[mf][nf] = __builtin_amdgcn_mfma_f32_16x16x32_bf16(
                        a0[mf], bv[nf], acc[mf][nf], 0, 0, 0);
            __builtin_amdgcn_s_setprio(0);
#pragma unroll
            for (int mf = 0; mf < 5; ++mf) { a0[mf] = a1[mf]; a1[mf] = a2[mf]; }
        };
#pragma unroll 1
        for (int kk = 0; kk < KCS; ++kk) {
            const int kc = kc0 + kk;
#pragma unroll
            for (int dy = 0; dy < 3; ++dy) {
                // all next-kc B stages issued at dy==0 (max latency cover)
                if (dy == 0 && kk + 1 < KCS) {
#pragma unroll
                    for (int it = 0; it < 9; ++it)
                        stageB(it, kc + 1, BSZ - curB);
                }
                const int dyi = curB + base2 + (ng + dy) * 2048;
                bf16x8 fm = *(const bf16x8*)&lds[dyi];
                bf16x8 f0 = *(const bf16x8*)&lds[dyi + 256];
                bf16x8 f1 = *(const bf16x8*)&lds[dyi + 512];
                bf16x8 f2 = *(const bf16x8*)&lds[dyi + 768];
                bf16x8 f3 = *(const bf16x8*)&lds[dyi + 1024];
                bf16x8 f4 = *(const bf16x8*)&lds[dyi + 1280];
                bf16x8 fp = *(const bf16x8*)&lds[dyi + 1536];
                doTap(dy * 3 + 0, kc, shm1(f0, fm), shm1(f1, f0), shm1(f2, f1),
                      shm1(f3, f2), shm1(f4, f3));
                doTap(dy * 3 + 1, kc, f0, f1, f2, f3, f4);
                doTap(dy * 3 + 2, kc, shp1(f0, f1), shp1(f1, f2), shp1(f2, f3),
                      shp1(f3, f4), shp1(f4, fp));
            }
            __syncthreads();
            curB = BSZ - curB;
        }
    } else {
        bf16x8 acur[5], anxt[5];
        loadA(acur, kc0);
#pragma unroll
        for (int it = 0; it < ITBv; ++it) stageB(it, kc0, 0);
        __syncthreads();
#pragma unroll 1
        for (int kk = 0; kk < KCS; ++kk) {
            const int kc = kc0 + kk;
#pragma unroll
            for (int tap = 0; tap < 9; ++tap) {
                if (tap < ITBv && kk + 1 < KCS)
                    stageB(tap, kc + 1, curB ^ BSZ);
                const int nstep = (tap == 8) ? (kc + 1) : ((tap + 1) * KC + kc);
                loadA(anxt, nstep);
                const int imm = ((tap / 3) * PW + (tap % 3)) * 16;
                __builtin_amdgcn_s_setprio(1);
#pragma unroll
                for (int nf = 0; nf < NF; ++nf) {
                    bf16x8 b = *(const bf16x8*)&lds[curB + blane[nf] + imm];
#pragma unroll
                    for (int mf = 0; mf < 5; ++mf)
                        acc[mf][nf] = __builtin_amdgcn_mfma_f32_16x16x32_bf16(
                            acur[mf], b, acc[mf][nf], 0, 0, 0);
                }
                __builtin_amdgcn_s_setprio(0);
#pragma unroll
                for (int mf = 0; mf < 5; ++mf) acur[mf] = anxt[mf];
            }
            __syncthreads();
            curB ^= BSZ;
        }
    }

    if constexpr (KS > 1) {
        float* pb = pbuf + (size_t)((n * TILES + tile) * KS + ks) * (160 * NT);
#pragma unroll
        for (int mf = 0; mf < 5; ++mf)
#pragma unroll
            for (int nf = 0; nf < NF; ++nf) {
                int col = (ng * NF + nf) * 16 + lr;
#pragma unroll
                for (int r = 0; r < 4; ++r) {
                    int ch = mhalf * 80 + mf * 16 + kg * 4 + r;
                    pb[ch * NT + col] = acc[mf][nf][r];
                }
            }
        return;
    } else {
        const float sc = scales[LVL];
        float* smf = (float*)lds;

        if (mhalf == 0) {
            float4 bias[5];
#pragma unroll
            for (int mf = 0; mf < 5; ++mf)
                bias[mf] = *(const float4*)(bc + mf * 16 + kg * 4);
#pragma unroll
            for (int nf = 0; nf < NF; ++nf) {
                int p = p0 + (ng * NF + nf) * 16 + lr;
                if (p < HW) {
                    float* oc = out_cls + ((size_t)n * A_TOTAL + A_OFFp + p) * NCLS;
#pragma unroll
                    for (int mf = 0; mf < 5; ++mf) {
                        f32x4 v = acc[mf][nf];
                        float4 s;
                        s.x = fsig(v[0] + bias[mf].x);
                        s.y = fsig(v[1] + bias[mf].y);
                        s.z = fsig(v[2] + bias[mf].z);
                        s.w = fsig(v[3] + bias[mf].w);
                        *(float4*)(oc + mf * 16 + kg * 4) = s;
                    }
                }
            }
        } else {
#pragma unroll
            for (int mf = 0; mf < 5; ++mf)
#pragma unroll
                for (int nf = 0; nf < NF; ++nf) {
                    int lpx = (ng * NF + nf) * 16 + lr;
#pragma unroll
                    for (int r = 0; r < 4; ++r) {
                        int ch = mf * 16 + kg * 4 + r;
                        if (ch < 68) smf[ch * (NT + 4) + lpx] = acc[mf][nf][r];
                    }
                }
        }
        __syncthreads();

        for (int u = tid; u < 4 * NT; u += NTHR) {
            int f   = u / NT;
            int lpx = u % NT;
            int p   = p0 + lpx;
            if (p < HW) {
                float lg[17];
                float m = -1e30f;
#pragma unroll
                for (int r = 0; r < 17; ++r) {
                    lg[r] = (smf[(f * 17 + r) * (NT + 4) + lpx] + br[f * 17 + r]) * sc;
                    m = fmaxf(m, lg[r]);
                }
                float ssum = 0.f, esum = 0.f;
#pragma unroll
                for (int r = 0; r < 17; ++r) {
                    float e = __expf(lg[r] - m);
                    ssum += e;
                    esum += e * (float)r;
                }
                const float dist = esum * __builtin_amdgcn_rcpf(ssum) * (float)STRIDE;
                const int py = p / W, px = p % W;
                const float base = (f & 1) ? (float)(py * STRIDE) : (float)(px * STRIDE);
                const float val  = (f < 2) ? (base - dist) : (base + dist);
                out_box[((size_t)n * A_TOTAL + A_OFFp + p) * 4 + f] = val;
            }
        }
    }
}

// ---------------------------------------------------------------------------
// Split-K reduce + epilogue (NT=64 tiles), fast exp.
// ---------------------------------------------------------------------------
template<int H, int W, int STRIDE, int A_OFFp, int LVL, int TILES, int KS>
__global__ __launch_bounds__(256) void reduce_epi(
    const float* __restrict__ pbuf,
    const float* __restrict__ bc, const float* __restrict__ br,
    const float* __restrict__ scales,
    float* __restrict__ out_cls, float* __restrict__ out_box) {
    constexpr int HW = H * W;
    const int bid  = blockIdx.x;
    const int tile = bid % TILES;
    const int n    = bid / TILES;
    const int tid  = threadIdx.x;
    const float* pb = pbuf + (size_t)(n * TILES + tile) * KS * 10240;

    __shared__ float smf[160 * 66];
    for (int idx = tid; idx < 160 * 64; idx += 256) {
        float s = 0.f;
#pragma unroll
        for (int k = 0; k < KS; ++k) s += pb[k * 10240 + idx];
        smf[(idx >> 6) * 66 + (idx & 63)] = s;
    }
    __syncthreads();

    const int q = tid >> 6;
    const int t = tid & 63;
    const int p = tile * 64 + t;
    if (p < HW) {
        float* oc = out_cls + ((size_t)n * A_TOTAL + A_OFFp + p) * NCLS + q * 20;
#pragma unroll
        for (int k = 0; k < 20; k += 4) {
            float4 v;
            v.x = fsig(smf[(q * 20 + k + 0) * 66 + t] + bc[q * 20 + k + 0]);
            v.y = fsig(smf[(q * 20 + k + 1) * 66 + t] + bc[q * 20 + k + 1]);
            v.z = fsig(smf[(q * 20 + k + 2) * 66 + t] + bc[q * 20 + k + 2]);
            v.w = fsig(smf[(q * 20 + k + 3) * 66 + t] + bc[q * 20 + k + 3]);
            *(float4*)(oc + k) = v;
        }
        const float sc = scales[LVL];
        float lg[17];
        float m = -1e30f;
#pragma unroll
        for (int r = 0; r < 17; ++r) {
            lg[r] = (smf[(80 + q * 17 + r) * 66 + t] + br[q * 17 + r]) * sc;
            m = fmaxf(m, lg[r]);
        }
        float ssum = 0.f, esum = 0.f;
#pragma unroll
        for (int r = 0; r < 17; ++r) {
            float e = __expf(lg[r] - m);
            ssum += e;
            esum += e * (float)r;
        }
        const float dist = esum * __builtin_amdgcn_rcpf(ssum) * (float)STRIDE;
        const int py = p / W, px = p % W;
        const float base = (q & 1) ? (float)(py * STRIDE) : (float)(px * STRIDE);
        const float val  = (q < 2) ? (base - dist) : (base + dist);
        out_box[((size_t)n * A_TOTAL + A_OFFp + p) * 4 + q] = val;
    }
}

extern "C" void kernel_launch(void* const* d_in, const int* in_sizes, int n_in,
                              void* d_out, int out_size, void* d_ws, size_t ws_size,
                              hipStream_t stream) {
    const float* x0  = (const float*)d_in[0];
    const float* x1  = (const float*)d_in[1];
    const float* x2  = (const float*)d_in[2];
    const float* wc0 = (const float*)d_in[3];
    const float* bc0 = (const float*)d_in[4];
    const float* wr0 = (const float*)d_in[5];
    const float* br0 = (const float*)d_in[6];
    const float* wc1 = (const float*)d_in[7];
    const float* bc1 = (const float*)d_in[8];
    const float* wr1 = (const float*)d_in[9];
    const float* br1 = (const float*)d_in[10];
    const float* wc2 = (const float*)d_in[11];
    const float* bc2 = (const float*)d_in[12];
    const float* wr2 = (const float*)d_in[13];
    const float* br2 = (const float*)d_in[14];
    const float* scl = (const float*)d_in[15];

    float* out_cls = (float*)d_out;
    float* out_box = (float*)d_out + (size_t)BATCH * A_TOTAL * NCLS;

    __hip_bfloat16* af  = (__hip_bfloat16*)d_ws;
    __hip_bfloat16* af0 = af;
    __hip_bfloat16* af1 = af + 184320;
    __hip_bfloat16* af2 = af + 552960;
    __hip_bfloat16* xT  = af + 1290240;   // padded image region, reused per level
    float* pbuf = (float*)((char*)xT + 15859712);

    prep_w_all<<<dim3(630), 256, 0, stream>>>(wc0, wr0, wc1, wr1, wc2, wr2,
                                              af0, af1, af2);

    // L0: DPP row-aligned tile NT=160 (2 rows), NF=5, WEU=2, A-depth 2
    transpose_x<128, 80, 80><<<dim3(32 * 80 * 2), 256, 0, stream>>>(x0, xT);
    gemm_head<128, 80, 80, 8, 0, 0, 160, 1, 256, 2, 1><<<dim3(32 * 40), 256, 0, stream>>>(
        xT, af0, bc0, br0, scl, out_cls, out_box, nullptr);

    // L1: 512-thr NT=128 (NF=2) WEU=4 (R10 best: 416 blocks, one-round fill)
    transpose_x<256, 40, 40><<<dim3(32 * 40 * 4), 256, 0, stream>>>(x1, xT);
    gemm_head<256, 40, 40, 16, 6400, 1, 128, 1, 512, 4, 0><<<dim3(32 * 13), 512, 0, stream>>>(
        xT, af1, bc1, br1, scl, out_cls, out_box, nullptr);

    // L2: NT=64, split-K KS=4, 256-thr, WEU=4 (NF=2 fits) -> 896 blocks
    transpose_x<512, 20, 20><<<dim3(32 * 20 * 8), 256, 0, stream>>>(x2, xT);
    gemm_head<512, 20, 20, 32, 8000, 2, 64, 4, 256, 4, 0><<<dim3(32 * 7 * 4), 256, 0, stream>>>(
        xT, af2, bc2, br2, scl, out_cls, out_box, pbuf);
    reduce_epi<20, 20, 32, 8000, 2, 7, 4><<<dim3(32 * 7), 256, 0, stream>>>(
        pbuf, bc2, br2, scl, out_cls, out_box);
}

// Round 21
// 241.085 us; speedup vs baseline: 1.0347x; 1.0347x over previous
//
#include <hip/hip_runtime.h>
#include <hip/hip_bf16.h>
#include <math.h>

#define BATCH   32
#define A_TOTAL 8400
#define NCLS    80

typedef __attribute__((ext_vector_type(8))) short bf16x8;
typedef __attribute__((ext_vector_type(4))) float f32x4;

__device__ __forceinline__ short f2bf(float f) {
    union { float f; unsigned u; } v; v.f = f;
    unsigned u = v.u + 0x7fffu + ((v.u >> 16) & 1u);   // round-nearest-even
    return (short)(u >> 16);
}

// fast sigmoid: v_exp_f32 + v_rcp_f32 (error ~2^-21, way under bf16-conv noise)
__device__ __forceinline__ float fsig(float x) {
    return __builtin_amdgcn_rcpf(1.f + __expf(-x));
}

// async global->LDS, 16B per lane; lds dest = wave-uniform base + lane*16
__device__ __forceinline__ void stage16(const void* g, void* ldsp) {
    __builtin_amdgcn_global_load_lds(
        (const __attribute__((address_space(1))) unsigned int*)g,
        (__attribute__((address_space(3))) unsigned int*)ldsp, 16, 0, 0);
}

// DPP pixel shifts within 16-lane rows (frag = 16 consecutive pixels/lane).
// NOTE (R20 lesson): A-prefetch depth is 1 at EVERY occupancy point —
// depth 2 spills regardless of WEU (R13/R14/R20: +5-13MB scratch traffic).
__device__ __forceinline__ bf16x8 shp1(bf16x8 cur, bf16x8 nxt) {   // pixel +1
    union { bf16x8 v; int d[4]; } c{cur}, n{nxt}, r;
#pragma unroll
    for (int i = 0; i < 4; ++i) {
        int t = __builtin_amdgcn_update_dpp(0, n.d[i], 0x11F, 0xF, 0xF, false);
        r.d[i] = __builtin_amdgcn_update_dpp(t, c.d[i], 0x101, 0xF, 0xF, false);
    }
    return r.v;
}
__device__ __forceinline__ bf16x8 shm1(bf16x8 cur, bf16x8 prv) {   // pixel -1
    union { bf16x8 v; int d[4]; } c{cur}, p{prv}, r;
#pragma unroll
    for (int i = 0; i < 4; ++i) {
        int t = __builtin_amdgcn_update_dpp(0, p.d[i], 0x10F, 0xF, 0xF, false);
        r.d[i] = __builtin_amdgcn_update_dpp(t, c.d[i], 0x111, 0xF, 0xF, false);
    }
    return r.v;
}

// ---------------------------------------------------------------------------
// Weight prep (all 3 levels in ONE launch):
// Afrag[tap][kc][mf(10)][lane(64)][8] bf16, M padded 148->160.
// ---------------------------------------------------------------------------
__device__ __forceinline__ void prep_w_body(const float* wc, const float* wr,
                                            __hip_bfloat16* af, int C, int bidl) {
    const int KC = C / 32;
    const int total = 9 * KC * 10 * 64;
    int idx = bidl * 256 + threadIdx.x;
    if (idx >= total) return;
    int l   = idx & 63;
    int rem = idx >> 6;
    int mf  = rem % 10;
    int kc  = (rem / 10) % KC;
    int tap = rem / (10 * KC);
    int m     = mf * 16 + (l & 15);
    int cbase = kc * 32 + (l >> 4) * 8;
    short v[8];
#pragma unroll
    for (int j = 0; j < 8; ++j) {
        int c = cbase + j;
        float w = 0.f;
        if (m < 80)        w = wc[((size_t)m * C + c) * 9 + tap];
        else if (m < 148)  w = wr[((size_t)(m - 80) * C + c) * 9 + tap];
        v[j] = f2bf(w);
    }
    *(bf16x8*)((short*)af + (size_t)idx * 8) = *(bf16x8*)v;
}

__global__ __launch_bounds__(256) void prep_w_all(
    const float* __restrict__ wc0, const float* __restrict__ wr0,
    const float* __restrict__ wc1, const float* __restrict__ wr1,
    const float* __restrict__ wc2, const float* __restrict__ wr2,
    __hip_bfloat16* __restrict__ af0, __hip_bfloat16* __restrict__ af1,
    __hip_bfloat16* __restrict__ af2) {
    int b = blockIdx.x;
    if (b < 90)       prep_w_body(wc0, wr0, af0, 128, b);
    else if (b < 270) prep_w_body(wc1, wr1, af1, 256, b - 90);
    else              prep_w_body(wc2, wr2, af2, 512, b - 270);
}

// ---------------------------------------------------------------------------
// NCHW fp32 -> zero-padded xT[n][kc][j(4)][(H+2)(W+2)][8 bf16].
// ---------------------------------------------------------------------------
template<int C, int H, int W>
__global__ __launch_bounds__(256) void transpose_x(const float* __restrict__ x,
                                                   __hip_bfloat16* __restrict__ xT) {
    const int CC  = C / 64;
    const int KC  = C / 32;
    const int PW  = W + 2;
    const int PHW = (H + 2) * PW;
    int b   = blockIdx.x;
    int cch = b % CC;
    int y   = (b / CC) % H;
    int n   = b / (CC * H);
    __shared__ float sm[64][W + 1];
    const float* src = x + (((size_t)n * C + cch * 64) * H + y) * W;
    for (int i = threadIdx.x; i < 64 * (W / 4); i += 256) {
        int c = i / (W / 4), f4 = i % (W / 4);
        float4 v = *(const float4*)(src + (size_t)c * H * W + f4 * 4);
        sm[c][f4 * 4 + 0] = v.x;
        sm[c][f4 * 4 + 1] = v.y;
        sm[c][f4 * 4 + 2] = v.z;
        sm[c][f4 * 4 + 3] = v.w;
    }
    __syncthreads();
    short* base = (short*)xT + (size_t)n * KC * 4 * PHW * 8;
    for (int u = threadIdx.x; u < W * 8; u += 256) {
        int g8 = u / W, xc = u % W;
        int kc = cch * 2 + (g8 >> 2);
        int j  = g8 & 3;
        short v[8];
#pragma unroll
        for (int jj = 0; jj < 8; ++jj) v[jj] = f2bf(sm[g8 * 8 + jj][xc]);
        *(bf16x8*)(base + (((size_t)(kc * 4 + j)) * PHW + (y + 1) * PW + xc + 1) * 8) =
            *(bf16x8*)v;
    }
    bf16x8 z = (bf16x8)(short)0;
    if (threadIdx.x < 16) {
        int g8 = threadIdx.x >> 1, side = threadIdx.x & 1;
        int kc = cch * 2 + (g8 >> 2), j = g8 & 3;
        *(bf16x8*)(base + (((size_t)(kc * 4 + j)) * PHW + (y + 1) * PW + side * (W + 1)) * 8) = z;
    }
    if (y == 0) {
        for (int u = threadIdx.x; u < PW * 8; u += 256) {
            int g8 = u / PW, col = u % PW;
            int kc = cch * 2 + (g8 >> 2), j = g8 & 3;
            *(bf16x8*)(base + (((size_t)(kc * 4 + j)) * PHW + col) * 8) = z;
        }
    }
    if (y == H - 1) {
        for (int u = threadIdx.x; u < PW * 8; u += 256) {
            int g8 = u / PW, col = u % PW;
            int kc = cch * 2 + (g8 >> 2), j = g8 & 3;
            *(bf16x8*)(base + (((size_t)(kc * 4 + j)) * PHW + (H + 1) * PW + col) * 8) = z;
        }
    }
}

// ---------------------------------------------------------------------------
// Implicit-GEMM head on zero-padded image.
// DPPB==0: flat-window LDS B, 9 taps, per-tap ds_reads (L1/L2 path).
// DPPB==1 (L0): row-aligned NT=160 tile (2 image rows, ng=row, NF=5, WEU=2).
//   B staged as 4 padded rows [j(4)][515 granules]; per dy read 7 frags;
//   dx=+-1 taps derived by DPP lane-shifts (no LDS read). A depth-1 prefetch.
// ---------------------------------------------------------------------------
template<int C, int H, int W, int STRIDE, int A_OFFp, int LVL, int NT, int KS,
         int NTHR, int WEU, int DPPB>
__global__ __launch_bounds__(NTHR, WEU) void gemm_head(
    const __hip_bfloat16* __restrict__ xT,
    const __hip_bfloat16* __restrict__ af,
    const float* __restrict__ bc, const float* __restrict__ br,
    const float* __restrict__ scales,
    float* __restrict__ out_cls, float* __restrict__ out_box,
    float* __restrict__ pbuf) {
    constexpr int HW     = H * W;
    constexpr int PW     = W + 2;
    constexpr int PHW    = (H + 2) * PW;
    constexpr int WAVES  = NTHR / 64;
    constexpr int WN     = WAVES / 2;
    constexpr int NF     = NT / (16 * WN);
    static_assert(NT == WN * NF * 16, "NT must equal WN*NF*16");
    static_assert(!DPPB || (NF == 5 && W == 80 && NT == 160 && NTHR == 256 && KS == 1),
                  "DPP path assumes 2-row 160px tile");
    constexpr int TILES  = (HW + NT - 1) / NT;
    constexpr int KC     = C / 32;
    constexpr int KCS    = KC / KS;
    constexpr int DYMAX  = (NT - 1) / W + 1;
    constexpr int NSTAGE = NT + 2 * DYMAX + 2 * W + 7;
    constexpr int NS16   = NSTAGE * 16;
    constexpr int NG     = NSTAGE * 4;
    constexpr int ITBv   = DPPB ? 9 : ((NG + NTHR - 1) / NTHR);
    constexpr int BSZ    = DPPB ? (9 * NTHR * 16) : (ITBv * NTHR * 16);
    constexpr int EPI    = 68 * (NT + 4) * 4;
    constexpr int LDSB   = (KS > 1) ? (2 * BSZ) : ((2 * BSZ) > EPI ? (2 * BSZ) : EPI);
    static_assert(ITBv <= 9, "B staging spread exceeds tap steps");

    __shared__ __align__(16) char lds[LDSB];

    constexpr int NWG = BATCH * TILES * KS;
    const int bid  = blockIdx.x;
    const int swz  = (bid & 7) * (NWG / 8) + (bid >> 3);
    const int ks   = swz % KS;
    const int rest = swz / KS;
    const int tile = rest % TILES;
    const int n    = rest / TILES;

    const int tid   = threadIdx.x;
    const int l     = tid & 63;
    const int wid   = __builtin_amdgcn_readfirstlane(tid >> 6);
    const int mhalf = wid & 1;
    const int ng    = wid >> 1;      // n-group (DPPB: output image row within tile)
    const int lr    = l & 15;
    const int kg    = l >> 4;

    const char* xb  = (const char*)xT + (size_t)n * KC * 4 * PHW * 16;
    const char* afc = (const char*)af;

    const int p0    = tile * NT;

    int blane[NF];
    unsigned bsoff[ITBv];
    int base2 = 0;
    if constexpr (DPPB) {
        base2 = (kg * 515 + lr + 1) * 16;
#pragma unroll
        for (int it = 0; it < ITBv; ++it) {
            int idx = it * NTHR + tid; if (idx > 2059) idx = 2059;
            int j = idx / 515;
            int rem = idx - j * 515; if (rem > 511) rem = 511;
            int g = rem >> 7, px = rem & 127;
            int pos = px - 16; pos = pos < 0 ? 0 : (pos > W + 1 ? W + 1 : pos);
            int q = (2 * tile + g) * PW + pos;
            bsoff[it] = (unsigned)((j * PHW + q) * 16);
        }
    } else {
        const int qbase = (p0 / W) * PW + (p0 % W);
#pragma unroll
        for (int nf = 0; nf < NF; ++nf) {
            int p  = p0 + (ng * NF + nf) * 16 + lr;
            int qc = (p / W + 1) * PW + (p % W) + 1;
            blane[nf] = kg * NS16 + (qc - (W + 3) - qbase) * 16;
        }
#pragma unroll
        for (int it = 0; it < ITBv; ++it) {
            int idx = it * NTHR + tid;
            int j = idx / NSTAGE; if (j > 3) j = 3;
            int q = qbase + (idx - j * NSTAGE);
            if (q > PHW - 1) q = PHW - 1;
            bsoff[it] = (unsigned)((j * PHW + q) * 16);
        }
    }

    f32x4 acc[5][NF];
#pragma unroll
    for (int mf = 0; mf < 5; ++mf)
#pragma unroll
        for (int nf = 0; nf < NF; ++nf) acc[mf][nf] = (f32x4)0.f;

    auto stageB = [&](int it, int kc, unsigned dstbase) {
        stage16(xb + (size_t)kc * (4 * PHW * 16) + bsoff[it],
                &lds[dstbase + it * (NTHR * 16) + wid * 1024]);
    };
    auto loadA = [&](bf16x8* dst, int step) {
        const char* asrc = afc + (size_t)step * 10240 + mhalf * 5120 + l * 16;
#pragma unroll
        for (int mf = 0; mf < 5; ++mf)
            dst[mf] = *(const bf16x8*)(asrc + mf * 1024);
    };

    const int kc0 = ks * KCS;

    unsigned curB = 0;

    if constexpr (DPPB) {
        bf16x8 acur[5], anxt[5];
        loadA(acur, kc0);          // (tap0, kc0)
#pragma unroll
        for (int it = 0; it < ITBv; ++it) stageB(it, kc0, 0);
        __syncthreads();

        auto doTap = [&](int tap, int kc, bf16x8 b0, bf16x8 b1, bf16x8 b2,
                         bf16x8 b3, bf16x8 b4) {
            const int nstep = (tap == 8) ? (kc + 1) : ((tap + 1) * KC + kc);
            loadA(anxt, nstep);
            bf16x8 bv[5] = {b0, b1, b2, b3, b4};
            __builtin_amdgcn_s_setprio(1);
#pragma unroll
            for (int nf = 0; nf < 5; ++nf)
#pragma unroll
                for (int mf = 0; mf < 5; ++mf)
                    acc[mf][nf] = __builtin_amdgcn_mfma_f32_16x16x32_bf16(
                        acur[mf], bv[nf], acc[mf][nf], 0, 0, 0);
            __builtin_amdgcn_s_setprio(0);
#pragma unroll
            for (int mf = 0; mf < 5; ++mf) acur[mf] = anxt[mf];
        };
#pragma unroll 1
        for (int kk = 0; kk < KCS; ++kk) {
            const int kc = kc0 + kk;
#pragma unroll
            for (int dy = 0; dy < 3; ++dy) {
                if (kk + 1 < KCS) {
#pragma unroll
                    for (int it = dy * 3; it < dy * 3 + 3; ++it)
                        stageB(it, kc + 1, BSZ - curB);
                }
                const int dyi = curB + base2 + (ng + dy) * 2048;
                bf16x8 fm = *(const bf16x8*)&lds[dyi];
                bf16x8 f0 = *(const bf16x8*)&lds[dyi + 256];
                bf16x8 f1 = *(const bf16x8*)&lds[dyi + 512];
                bf16x8 f2 = *(const bf16x8*)&lds[dyi + 768];
                bf16x8 f3 = *(const bf16x8*)&lds[dyi + 1024];
                bf16x8 f4 = *(const bf16x8*)&lds[dyi + 1280];
                bf16x8 fp = *(const bf16x8*)&lds[dyi + 1536];
                doTap(dy * 3 + 0, kc, shm1(f0, fm), shm1(f1, f0), shm1(f2, f1),
                      shm1(f3, f2), shm1(f4, f3));
                doTap(dy * 3 + 1, kc, f0, f1, f2, f3, f4);
                doTap(dy * 3 + 2, kc, shp1(f0, f1), shp1(f1, f2), shp1(f2, f3),
                      shp1(f3, f4), shp1(f4, fp));
            }
            __syncthreads();
            curB = BSZ - curB;
        }
    } else {
        bf16x8 acur[5], anxt[5];
        loadA(acur, kc0);
#pragma unroll
        for (int it = 0; it < ITBv; ++it) stageB(it, kc0, 0);
        __syncthreads();
#pragma unroll 1
        for (int kk = 0; kk < KCS; ++kk) {
            const int kc = kc0 + kk;
#pragma unroll
            for (int tap = 0; tap < 9; ++tap) {
                if (tap < ITBv && kk + 1 < KCS)
                    stageB(tap, kc + 1, curB ^ BSZ);
                const int nstep = (tap == 8) ? (kc + 1) : ((tap + 1) * KC + kc);
                loadA(anxt, nstep);
                const int imm = ((tap / 3) * PW + (tap % 3)) * 16;
                __builtin_amdgcn_s_setprio(1);
#pragma unroll
                for (int nf = 0; nf < NF; ++nf) {
                    bf16x8 b = *(const bf16x8*)&lds[curB + blane[nf] + imm];
#pragma unroll
                    for (int mf = 0; mf < 5; ++mf)
                        acc[mf][nf] = __builtin_amdgcn_mfma_f32_16x16x32_bf16(
                            acur[mf], b, acc[mf][nf], 0, 0, 0);
                }
                __builtin_amdgcn_s_setprio(0);
#pragma unroll
                for (int mf = 0; mf < 5; ++mf) acur[mf] = anxt[mf];
            }
            __syncthreads();
            curB ^= BSZ;
        }
    }

    if constexpr (KS > 1) {
        float* pb = pbuf + (size_t)((n * TILES + tile) * KS + ks) * (160 * NT);
#pragma unroll
        for (int mf = 0; mf < 5; ++mf)
#pragma unroll
            for (int nf = 0; nf < NF; ++nf) {
                int col = (ng * NF + nf) * 16 + lr;
#pragma unroll
                for (int r = 0; r < 4; ++r) {
                    int ch = mhalf * 80 + mf * 16 + kg * 4 + r;
                    pb[ch * NT + col] = acc[mf][nf][r];
                }
            }
        return;
    } else {
        const float sc = scales[LVL];
        float* smf = (float*)lds;

        if (mhalf == 0) {
            float4 bias[5];
#pragma unroll
            for (int mf = 0; mf < 5; ++mf)
                bias[mf] = *(const float4*)(bc + mf * 16 + kg * 4);
#pragma unroll
            for (int nf = 0; nf < NF; ++nf) {
                int p = p0 + (ng * NF + nf) * 16 + lr;
                if (p < HW) {
                    float* oc = out_cls + ((size_t)n * A_TOTAL + A_OFFp + p) * NCLS;
#pragma unroll
                    for (int mf = 0; mf < 5; ++mf) {
                        f32x4 v = acc[mf][nf];
                        float4 s;
                        s.x = fsig(v[0] + bias[mf].x);
                        s.y = fsig(v[1] + bias[mf].y);
                        s.z = fsig(v[2] + bias[mf].z);
                        s.w = fsig(v[3] + bias[mf].w);
                        *(float4*)(oc + mf * 16 + kg * 4) = s;
                    }
                }
            }
        } else {
#pragma unroll
            for (int mf = 0; mf < 5; ++mf)
#pragma unroll
                for (int nf = 0; nf < NF; ++nf) {
                    int lpx = (ng * NF + nf) * 16 + lr;
#pragma unroll
                    for (int r = 0; r < 4; ++r) {
                        int ch = mf * 16 + kg * 4 + r;
                        if (ch < 68) smf[ch * (NT + 4) + lpx] = acc[mf][nf][r];
                    }
                }
        }
        __syncthreads();

        for (int u = tid; u < 4 * NT; u += NTHR) {
            int f   = u / NT;
            int lpx = u % NT;
            int p   = p0 + lpx;
            if (p < HW) {
                float lg[17];
                float m = -1e30f;
#pragma unroll
                for (int r = 0; r < 17; ++r) {
                    lg[r] = (smf[(f * 17 + r) * (NT + 4) + lpx] + br[f * 17 + r]) * sc;
                    m = fmaxf(m, lg[r]);
                }
                float ssum = 0.f, esum = 0.f;
#pragma unroll
                for (int r = 0; r < 17; ++r) {
                    float e = __expf(lg[r] - m);
                    ssum += e;
                    esum += e * (float)r;
                }
                const float dist = esum * __builtin_amdgcn_rcpf(ssum) * (float)STRIDE;
                const int py = p / W, px = p % W;
                const float base = (f & 1) ? (float)(py * STRIDE) : (float)(px * STRIDE);
                const float val  = (f < 2) ? (base - dist) : (base + dist);
                out_box[((size_t)n * A_TOTAL + A_OFFp + p) * 4 + f] = val;
            }
        }
    }
}

// ---------------------------------------------------------------------------
// Split-K reduce + epilogue (NT=64 tiles), fast exp.
// ---------------------------------------------------------------------------
template<int H, int W, int STRIDE, int A_OFFp, int LVL, int TILES, int KS>
__global__ __launch_bounds__(256) void reduce_epi(
    const float* __restrict__ pbuf,
    const float* __restrict__ bc, const float* __restrict__ br,
    const float* __restrict__ scales,
    float* __restrict__ out_cls, float* __restrict__ out_box) {
    constexpr int HW = H * W;
    const int bid  = blockIdx.x;
    const int tile = bid % TILES;
    const int n    = bid / TILES;
    const int tid  = threadIdx.x;
    const float* pb = pbuf + (size_t)(n * TILES + tile) * KS * 10240;

    __shared__ float smf[160 * 66];
    for (int idx = tid; idx < 160 * 64; idx += 256) {
        float s = 0.f;
#pragma unroll
        for (int k = 0; k < KS; ++k) s += pb[k * 10240 + idx];
        smf[(idx >> 6) * 66 + (idx & 63)] = s;
    }
    __syncthreads();

    const int q = tid >> 6;
    const int t = tid & 63;
    const int p = tile * 64 + t;
    if (p < HW) {
        float* oc = out_cls + ((size_t)n * A_TOTAL + A_OFFp + p) * NCLS + q * 20;
#pragma unroll
        for (int k = 0; k < 20; k += 4) {
            float4 v;
            v.x = fsig(smf[(q * 20 + k + 0) * 66 + t] + bc[q * 20 + k + 0]);
            v.y = fsig(smf[(q * 20 + k + 1) * 66 + t] + bc[q * 20 + k + 1]);
            v.z = fsig(smf[(q * 20 + k + 2) * 66 + t] + bc[q * 20 + k + 2]);
            v.w = fsig(smf[(q * 20 + k + 3) * 66 + t] + bc[q * 20 + k + 3]);
            *(float4*)(oc + k) = v;
        }
        const float sc = scales[LVL];
        float lg[17];
        float m = -1e30f;
#pragma unroll
        for (int r = 0; r < 17; ++r) {
            lg[r] = (smf[(80 + q * 17 + r) * 66 + t] + br[q * 17 + r]) * sc;
            m = fmaxf(m, lg[r]);
        }
        float ssum = 0.f, esum = 0.f;
#pragma unroll
        for (int r = 0; r < 17; ++r) {
            float e = __expf(lg[r] - m);
            ssum += e;
            esum += e * (float)r;
        }
        const float dist = esum * __builtin_amdgcn_rcpf(ssum) * (float)STRIDE;
        const int py = p / W, px = p % W;
        const float base = (q & 1) ? (float)(py * STRIDE) : (float)(px * STRIDE);
        const float val  = (q < 2) ? (base - dist) : (base + dist);
        out_box[((size_t)n * A_TOTAL + A_OFFp + p) * 4 + q] = val;
    }
}

extern "C" void kernel_launch(void* const* d_in, const int* in_sizes, int n_in,
                              void* d_out, int out_size, void* d_ws, size_t ws_size,
                              hipStream_t stream) {
    const float* x0  = (const float*)d_in[0];
    const float* x1  = (const float*)d_in[1];
    const float* x2  = (const float*)d_in[2];
    const float* wc0 = (const float*)d_in[3];
    const float* bc0 = (const float*)d_in[4];
    const float* wr0 = (const float*)d_in[5];
    const float* br0 = (const float*)d_in[6];
    const float* wc1 = (const float*)d_in[7];
    const float* bc1 = (const float*)d_in[8];
    const float* wr1 = (const float*)d_in[9];
    const float* br1 = (const float*)d_in[10];
    const float* wc2 = (const float*)d_in[11];
    const float* bc2 = (const float*)d_in[12];
    const float* wr2 = (const float*)d_in[13];
    const float* br2 = (const float*)d_in[14];
    const float* scl = (const float*)d_in[15];

    float* out_cls = (float*)d_out;
    float* out_box = (float*)d_out + (size_t)BATCH * A_TOTAL * NCLS;

    __hip_bfloat16* af  = (__hip_bfloat16*)d_ws;
    __hip_bfloat16* af0 = af;
    __hip_bfloat16* af1 = af + 184320;
    __hip_bfloat16* af2 = af + 552960;
    __hip_bfloat16* xT  = af + 1290240;   // padded image region, reused per level
    float* pbuf = (float*)((char*)xT + 15859712);

    prep_w_all<<<dim3(630), 256, 0, stream>>>(wc0, wr0, wc1, wr1, wc2, wr2,
                                              af0, af1, af2);

    // L0: DPP row-aligned tile NT=160 (2 rows), NF=5, WEU=2 -> 1280 blocks
    transpose_x<128, 80, 80><<<dim3(32 * 80 * 2), 256, 0, stream>>>(x0, xT);
    gemm_head<128, 80, 80, 8, 0, 0, 160, 1, 256, 2, 1><<<dim3(32 * 40), 256, 0, stream>>>(
        xT, af0, bc0, br0, scl, out_cls, out_box, nullptr);

    // L1: 512-thr NT=128 (NF=2) WEU=4 (R10 best: 416 blocks, one-round fill)
    transpose_x<256, 40, 40><<<dim3(32 * 40 * 4), 256, 0, stream>>>(x1, xT);
    gemm_head<256, 40, 40, 16, 6400, 1, 128, 1, 512, 4, 0><<<dim3(32 * 13), 512, 0, stream>>>(
        xT, af1, bc1, br1, scl, out_cls, out_box, nullptr);

    // L2: NT=64, split-K KS=4, 256-thr, WEU=4 (NF=2 fits) -> 896 blocks
    transpose_x<512, 20, 20><<<dim3(32 * 20 * 8), 256, 0, stream>>>(x2, xT);
    gemm_head<512, 20, 20, 32, 8000, 2, 64, 4, 256, 4, 0><<<dim3(32 * 7 * 4), 256, 0, stream>>>(
        xT, af2, bc2, br2, scl, out_cls, out_box, pbuf);
    reduce_epi<20, 20, 32, 8000, 2, 7, 4><<<dim3(32 * 7), 256, 0, stream>>>(
        pbuf, bc2, br2, scl, out_cls, out_box);
}

// Round 22
// 239.238 us; speedup vs baseline: 1.0427x; 1.0077x over previous
//
#include <hip/hip_runtime.h>
#include <hip/hip_bf16.h>
#include <math.h>

#define BATCH   32
#define A_TOTAL 8400
#define NCLS    80

typedef __attribute__((ext_vector_type(8))) short bf16x8;
typedef __attribute__((ext_vector_type(4))) float f32x4;

__device__ __forceinline__ short f2bf(float f) {
    union { float f; unsigned u; } v; v.f = f;
    unsigned u = v.u + 0x7fffu + ((v.u >> 16) & 1u);   // round-nearest-even
    return (short)(u >> 16);
}

// fast sigmoid: v_exp_f32 + v_rcp_f32 (error ~2^-21, way under bf16-conv noise)
__device__ __forceinline__ float fsig(float x) {
    return __builtin_amdgcn_rcpf(1.f + __expf(-x));
}

// async global->LDS, 16B per lane; lds dest = wave-uniform base + lane*16
__device__ __forceinline__ void stage16(const void* g, void* ldsp) {
    __builtin_amdgcn_global_load_lds(
        (const __attribute__((address_space(1))) unsigned int*)g,
        (__attribute__((address_space(3))) unsigned int*)ldsp, 16, 0, 0);
}

// ---------------------------------------------------------------------------
// Weight prep (all 3 levels in ONE launch):
// Afrag[tap][kc][mf(10)][lane(64)][8] bf16, M padded 148->160.
// ---------------------------------------------------------------------------
__device__ __forceinline__ void prep_w_body(const float* wc, const float* wr,
                                            __hip_bfloat16* af, int C, int bidl) {
    const int KC = C / 32;
    const int total = 9 * KC * 10 * 64;
    int idx = bidl * 256 + threadIdx.x;
    if (idx >= total) return;
    int l   = idx & 63;
    int rem = idx >> 6;
    int mf  = rem % 10;
    int kc  = (rem / 10) % KC;
    int tap = rem / (10 * KC);
    int m     = mf * 16 + (l & 15);
    int cbase = kc * 32 + (l >> 4) * 8;
    short v[8];
#pragma unroll
    for (int j = 0; j < 8; ++j) {
        int c = cbase + j;
        float w = 0.f;
        if (m < 80)        w = wc[((size_t)m * C + c) * 9 + tap];
        else if (m < 148)  w = wr[((size_t)(m - 80) * C + c) * 9 + tap];
        v[j] = f2bf(w);
    }
    *(bf16x8*)((short*)af + (size_t)idx * 8) = *(bf16x8*)v;
}

__global__ __launch_bounds__(256) void prep_w_all(
    const float* __restrict__ wc0, const float* __restrict__ wr0,
    const float* __restrict__ wc1, const float* __restrict__ wr1,
    const float* __restrict__ wc2, const float* __restrict__ wr2,
    __hip_bfloat16* __restrict__ af0, __hip_bfloat16* __restrict__ af1,
    __hip_bfloat16* __restrict__ af2) {
    int b = blockIdx.x;
    if (b < 90)       prep_w_body(wc0, wr0, af0, 128, b);
    else if (b < 270) prep_w_body(wc1, wr1, af1, 256, b - 90);
    else              prep_w_body(wc2, wr2, af2, 512, b - 270);
}

// ---------------------------------------------------------------------------
// NCHW fp32 -> zero-padded xT[n][kc][j(4)][(H+2)(W+2)][8 bf16].
// ---------------------------------------------------------------------------
template<int C, int H, int W>
__global__ __launch_bounds__(256) void transpose_x(const float* __restrict__ x,
                                                   __hip_bfloat16* __restrict__ xT) {
    const int CC  = C / 64;
    const int KC  = C / 32;
    const int PW  = W + 2;
    const int PHW = (H + 2) * PW;
    int b   = blockIdx.x;
    int cch = b % CC;
    int y   = (b / CC) % H;
    int n   = b / (CC * H);
    __shared__ float sm[64][W + 1];
    const float* src = x + (((size_t)n * C + cch * 64) * H + y) * W;
    for (int i = threadIdx.x; i < 64 * (W / 4); i += 256) {
        int c = i / (W / 4), f4 = i % (W / 4);
        float4 v = *(const float4*)(src + (size_t)c * H * W + f4 * 4);
        sm[c][f4 * 4 + 0] = v.x;
        sm[c][f4 * 4 + 1] = v.y;
        sm[c][f4 * 4 + 2] = v.z;
        sm[c][f4 * 4 + 3] = v.w;
    }
    __syncthreads();
    short* base = (short*)xT + (size_t)n * KC * 4 * PHW * 8;
    for (int u = threadIdx.x; u < W * 8; u += 256) {
        int g8 = u / W, xc = u % W;
        int kc = cch * 2 + (g8 >> 2);
        int j  = g8 & 3;
        short v[8];
#pragma unroll
        for (int jj = 0; jj < 8; ++jj) v[jj] = f2bf(sm[g8 * 8 + jj][xc]);
        *(bf16x8*)(base + (((size_t)(kc * 4 + j)) * PHW + (y + 1) * PW + xc + 1) * 8) =
            *(bf16x8*)v;
    }
    bf16x8 z = (bf16x8)(short)0;
    if (threadIdx.x < 16) {
        int g8 = threadIdx.x >> 1, side = threadIdx.x & 1;
        int kc = cch * 2 + (g8 >> 2), j = g8 & 3;
        *(bf16x8*)(base + (((size_t)(kc * 4 + j)) * PHW + (y + 1) * PW + side * (W + 1)) * 8) = z;
    }
    if (y == 0) {
        for (int u = threadIdx.x; u < PW * 8; u += 256) {
            int g8 = u / PW, col = u % PW;
            int kc = cch * 2 + (g8 >> 2), j = g8 & 3;
            *(bf16x8*)(base + (((size_t)(kc * 4 + j)) * PHW + col) * 8) = z;
        }
    }
    if (y == H - 1) {
        for (int u = threadIdx.x; u < PW * 8; u += 256) {
            int g8 = u / PW, col = u % PW;
            int kc = cch * 2 + (g8 >> 2), j = g8 & 3;
            *(bf16x8*)(base + (((size_t)(kc * 4 + j)) * PHW + (H + 1) * PW + col) * 8) = z;
        }
    }
}

// ---------------------------------------------------------------------------
// Implicit-GEMM head on zero-padded image.
// DPPB==0: flat-window LDS B, 9 taps, per-tap ds_reads (L1/L2 path).
// DPPB==1 (L0): row-aligned NT=160 tile (2 image rows, ng=row, NF=5, WEU=2).
//   B staged as 4 padded rows [j(4)][515 granules]; per (dy,dx) tap the 5
//   B-frags are DIRECT ds_reads at offset 256*(nf+1) + (dx-1)*16 — the row
//   window already holds the shifted bytes, so no DPP dependency chain sits
//   between LDS return and MFMA (R22: DPP chains were serializing the path).
// A depth-1 register prefetch (depth 2 spills at every WEU — R13/R14/R20).
// ---------------------------------------------------------------------------
template<int C, int H, int W, int STRIDE, int A_OFFp, int LVL, int NT, int KS,
         int NTHR, int WEU, int DPPB>
__global__ __launch_bounds__(NTHR, WEU) void gemm_head(
    const __hip_bfloat16* __restrict__ xT,
    const __hip_bfloat16* __restrict__ af,
    const float* __restrict__ bc, const float* __restrict__ br,
    const float* __restrict__ scales,
    float* __restrict__ out_cls, float* __restrict__ out_box,
    float* __restrict__ pbuf) {
    constexpr int HW     = H * W;
    constexpr int PW     = W + 2;
    constexpr int PHW    = (H + 2) * PW;
    constexpr int WAVES  = NTHR / 64;
    constexpr int WN     = WAVES / 2;
    constexpr int NF     = NT / (16 * WN);
    static_assert(NT == WN * NF * 16, "NT must equal WN*NF*16");
    static_assert(!DPPB || (NF == 5 && W == 80 && NT == 160 && NTHR == 256 && KS == 1),
                  "row path assumes 2-row 160px tile");
    constexpr int TILES  = (HW + NT - 1) / NT;
    constexpr int KC     = C / 32;
    constexpr int KCS    = KC / KS;
    constexpr int DYMAX  = (NT - 1) / W + 1;
    constexpr int NSTAGE = NT + 2 * DYMAX + 2 * W + 7;
    constexpr int NS16   = NSTAGE * 16;
    constexpr int NG     = NSTAGE * 4;
    constexpr int ITBv   = DPPB ? 9 : ((NG + NTHR - 1) / NTHR);
    constexpr int BSZ    = DPPB ? (9 * NTHR * 16) : (ITBv * NTHR * 16);
    constexpr int EPI    = 68 * (NT + 4) * 4;
    constexpr int LDSB   = (KS > 1) ? (2 * BSZ) : ((2 * BSZ) > EPI ? (2 * BSZ) : EPI);
    static_assert(ITBv <= 9, "B staging spread exceeds tap steps");

    __shared__ __align__(16) char lds[LDSB];

    constexpr int NWG = BATCH * TILES * KS;
    const int bid  = blockIdx.x;
    const int swz  = (bid & 7) * (NWG / 8) + (bid >> 3);
    const int ks   = swz % KS;
    const int rest = swz / KS;
    const int tile = rest % TILES;
    const int n    = rest / TILES;

    const int tid   = threadIdx.x;
    const int l     = tid & 63;
    const int wid   = __builtin_amdgcn_readfirstlane(tid >> 6);
    const int mhalf = wid & 1;
    const int ng    = wid >> 1;      // n-group (DPPB: output image row within tile)
    const int lr    = l & 15;
    const int kg    = l >> 4;

    const char* xb  = (const char*)xT + (size_t)n * KC * 4 * PHW * 16;
    const char* afc = (const char*)af;

    const int p0    = tile * NT;

    int blane[NF];
    unsigned bsoff[ITBv];
    int base2 = 0;
    if constexpr (DPPB) {
        base2 = (kg * 515 + lr + 1) * 16;
#pragma unroll
        for (int it = 0; it < ITBv; ++it) {
            int idx = it * NTHR + tid; if (idx > 2059) idx = 2059;
            int j = idx / 515;
            int rem = idx - j * 515; if (rem > 511) rem = 511;
            int g = rem >> 7, px = rem & 127;
            int pos = px - 16; pos = pos < 0 ? 0 : (pos > W + 1 ? W + 1 : pos);
            int q = (2 * tile + g) * PW + pos;
            bsoff[it] = (unsigned)((j * PHW + q) * 16);
        }
    } else {
        const int qbase = (p0 / W) * PW + (p0 % W);
#pragma unroll
        for (int nf = 0; nf < NF; ++nf) {
            int p  = p0 + (ng * NF + nf) * 16 + lr;
            int qc = (p / W + 1) * PW + (p % W) + 1;
            blane[nf] = kg * NS16 + (qc - (W + 3) - qbase) * 16;
        }
#pragma unroll
        for (int it = 0; it < ITBv; ++it) {
            int idx = it * NTHR + tid;
            int j = idx / NSTAGE; if (j > 3) j = 3;
            int q = qbase + (idx - j * NSTAGE);
            if (q > PHW - 1) q = PHW - 1;
            bsoff[it] = (unsigned)((j * PHW + q) * 16);
        }
    }

    f32x4 acc[5][NF];
#pragma unroll
    for (int mf = 0; mf < 5; ++mf)
#pragma unroll
        for (int nf = 0; nf < NF; ++nf) acc[mf][nf] = (f32x4)0.f;

    auto stageB = [&](int it, int kc, unsigned dstbase) {
        stage16(xb + (size_t)kc * (4 * PHW * 16) + bsoff[it],
                &lds[dstbase + it * (NTHR * 16) + wid * 1024]);
    };
    auto loadA = [&](bf16x8* dst, int step) {
        const char* asrc = afc + (size_t)step * 10240 + mhalf * 5120 + l * 16;
#pragma unroll
        for (int mf = 0; mf < 5; ++mf)
            dst[mf] = *(const bf16x8*)(asrc + mf * 1024);
    };

    const int kc0 = ks * KCS;

    unsigned curB = 0;

    if constexpr (DPPB) {
        bf16x8 acur[5], anxt[5];
        loadA(acur, kc0);          // (tap0, kc0)
#pragma unroll
        for (int it = 0; it < ITBv; ++it) stageB(it, kc0, 0);
        __syncthreads();

#pragma unroll 1
        for (int kk = 0; kk < KCS; ++kk) {
            const int kc = kc0 + kk;
#pragma unroll
            for (int dy = 0; dy < 3; ++dy) {
                if (kk + 1 < KCS) {
#pragma unroll
                    for (int it = dy * 3; it < dy * 3 + 3; ++it)
                        stageB(it, kc + 1, BSZ - curB);
                }
                const int dyi = curB + base2 + (ng + dy) * 2048;
#pragma unroll
                for (int dx = 0; dx < 3; ++dx) {
                    const int tap = dy * 3 + dx;
                    const int nstep = (tap == 8) ? (kc + 1) : ((tap + 1) * KC + kc);
                    loadA(anxt, nstep);
                    // direct shifted reads: frag nf at +256*(nf+1) + (dx-1)*16
                    const int off = dyi + (dx - 1) * 16;
                    bf16x8 b0 = *(const bf16x8*)&lds[off + 256];
                    bf16x8 b1 = *(const bf16x8*)&lds[off + 512];
                    bf16x8 b2 = *(const bf16x8*)&lds[off + 768];
                    bf16x8 b3 = *(const bf16x8*)&lds[off + 1024];
                    bf16x8 b4 = *(const bf16x8*)&lds[off + 1280];
                    bf16x8 bv[5] = {b0, b1, b2, b3, b4};
                    __builtin_amdgcn_s_setprio(1);
#pragma unroll
                    for (int nf = 0; nf < 5; ++nf)
#pragma unroll
                        for (int mf = 0; mf < 5; ++mf)
                            acc[mf][nf] = __builtin_amdgcn_mfma_f32_16x16x32_bf16(
                                acur[mf], bv[nf], acc[mf][nf], 0, 0, 0);
                    __builtin_amdgcn_s_setprio(0);
#pragma unroll
                    for (int mf = 0; mf < 5; ++mf) acur[mf] = anxt[mf];
                }
            }
            __syncthreads();
            curB = BSZ - curB;
        }
    } else {
        bf16x8 acur[5], anxt[5];
        loadA(acur, kc0);
#pragma unroll
        for (int it = 0; it < ITBv; ++it) stageB(it, kc0, 0);
        __syncthreads();
#pragma unroll 1
        for (int kk = 0; kk < KCS; ++kk) {
            const int kc = kc0 + kk;
#pragma unroll
            for (int tap = 0; tap < 9; ++tap) {
                if (tap < ITBv && kk + 1 < KCS)
                    stageB(tap, kc + 1, curB ^ BSZ);
                const int nstep = (tap == 8) ? (kc + 1) : ((tap + 1) * KC + kc);
                loadA(anxt, nstep);
                const int imm = ((tap / 3) * PW + (tap % 3)) * 16;
                __builtin_amdgcn_s_setprio(1);
#pragma unroll
                for (int nf = 0; nf < NF; ++nf) {
                    bf16x8 b = *(const bf16x8*)&lds[curB + blane[nf] + imm];
#pragma unroll
                    for (int mf = 0; mf < 5; ++mf)
                        acc[mf][nf] = __builtin_amdgcn_mfma_f32_16x16x32_bf16(
                            acur[mf], b, acc[mf][nf], 0, 0, 0);
                }
                __builtin_amdgcn_s_setprio(0);
#pragma unroll
                for (int mf = 0; mf < 5; ++mf) acur[mf] = anxt[mf];
            }
            __syncthreads();
            curB ^= BSZ;
        }
    }

    if constexpr (KS > 1) {
        float* pb = pbuf + (size_t)((n * TILES + tile) * KS + ks) * (160 * NT);
#pragma unroll
        for (int mf = 0; mf < 5; ++mf)
#pragma unroll
            for (int nf = 0; nf < NF; ++nf) {
                int col = (ng * NF + nf) * 16 + lr;
#pragma unroll
                for (int r = 0; r < 4; ++r) {
                    int ch = mhalf * 80 + mf * 16 + kg * 4 + r;
                    pb[ch * NT + col] = acc[mf][nf][r];
                }
            }
        return;
    } else {
        const float sc = scales[LVL];
        float* smf = (float*)lds;

        if (mhalf == 0) {
            float4 bias[5];
#pragma unroll
            for (int mf = 0; mf < 5; ++mf)
                bias[mf] = *(const float4*)(bc + mf * 16 + kg * 4);
#pragma unroll
            for (int nf = 0; nf < NF; ++nf) {
                int p = p0 + (ng * NF + nf) * 16 + lr;
                if (p < HW) {
                    float* oc = out_cls + ((size_t)n * A_TOTAL + A_OFFp + p) * NCLS;
#pragma unroll
                    for (int mf = 0; mf < 5; ++mf) {
                        f32x4 v = acc[mf][nf];
                        float4 s;
                        s.x = fsig(v[0] + bias[mf].x);
                        s.y = fsig(v[1] + bias[mf].y);
                        s.z = fsig(v[2] + bias[mf].z);
                        s.w = fsig(v[3] + bias[mf].w);
                        *(float4*)(oc + mf * 16 + kg * 4) = s;
                    }
                }
            }
        } else {
#pragma unroll
            for (int mf = 0; mf < 5; ++mf)
#pragma unroll
                for (int nf = 0; nf < NF; ++nf) {
                    int lpx = (ng * NF + nf) * 16 + lr;
#pragma unroll
                    for (int r = 0; r < 4; ++r) {
                        int ch = mf * 16 + kg * 4 + r;
                        if (ch < 68) smf[ch * (NT + 4) + lpx] = acc[mf][nf][r];
                    }
                }
        }
        __syncthreads();

        for (int u = tid; u < 4 * NT; u += NTHR) {
            int f   = u / NT;
            int lpx = u % NT;
            int p   = p0 + lpx;
            if (p < HW) {
                float lg[17];
                float m = -1e30f;
#pragma unroll
                for (int r = 0; r < 17; ++r) {
                    lg[r] = (smf[(f * 17 + r) * (NT + 4) + lpx] + br[f * 17 + r]) * sc;
                    m = fmaxf(m, lg[r]);
                }
                float ssum = 0.f, esum = 0.f;
#pragma unroll
                for (int r = 0; r < 17; ++r) {
                    float e = __expf(lg[r] - m);
                    ssum += e;
                    esum += e * (float)r;
                }
                const float dist = esum * __builtin_amdgcn_rcpf(ssum) * (float)STRIDE;
                const int py = p / W, px = p % W;
                const float base = (f & 1) ? (float)(py * STRIDE) : (float)(px * STRIDE);
                const float val  = (f < 2) ? (base - dist) : (base + dist);
                out_box[((size_t)n * A_TOTAL + A_OFFp + p) * 4 + f] = val;
            }
        }
    }
}

// ---------------------------------------------------------------------------
// Split-K reduce + epilogue (NT=64 tiles), fast exp.
// ---------------------------------------------------------------------------
template<int H, int W, int STRIDE, int A_OFFp, int LVL, int TILES, int KS>
__global__ __launch_bounds__(256) void reduce_epi(
    const float* __restrict__ pbuf,
    const float* __restrict__ bc, const float* __restrict__ br,
    const float* __restrict__ scales,
    float* __restrict__ out_cls, float* __restrict__ out_box) {
    constexpr int HW = H * W;
    const int bid  = blockIdx.x;
    const int tile = bid % TILES;
    const int n    = bid / TILES;
    const int tid  = threadIdx.x;
    const float* pb = pbuf + (size_t)(n * TILES + tile) * KS * 10240;

    __shared__ float smf[160 * 66];
    for (int idx = tid; idx < 160 * 64; idx += 256) {
        float s = 0.f;
#pragma unroll
        for (int k = 0; k < KS; ++k) s += pb[k * 10240 + idx];
        smf[(idx >> 6) * 66 + (idx & 63)] = s;
    }
    __syncthreads();

    const int q = tid >> 6;
    const int t = tid & 63;
    const int p = tile * 64 + t;
    if (p < HW) {
        float* oc = out_cls + ((size_t)n * A_TOTAL + A_OFFp + p) * NCLS + q * 20;
#pragma unroll
        for (int k = 0; k < 20; k += 4) {
            float4 v;
            v.x = fsig(smf[(q * 20 + k + 0) * 66 + t] + bc[q * 20 + k + 0]);
            v.y = fsig(smf[(q * 20 + k + 1) * 66 + t] + bc[q * 20 + k + 1]);
            v.z = fsig(smf[(q * 20 + k + 2) * 66 + t] + bc[q * 20 + k + 2]);
            v.w = fsig(smf[(q * 20 + k + 3) * 66 + t] + bc[q * 20 + k + 3]);
            *(float4*)(oc + k) = v;
        }
        const float sc = scales[LVL];
        float lg[17];
        float m = -1e30f;
#pragma unroll
        for (int r = 0; r < 17; ++r) {
            lg[r] = (smf[(80 + q * 17 + r) * 66 + t] + br[q * 17 + r]) * sc;
            m = fmaxf(m, lg[r]);
        }
        float ssum = 0.f, esum = 0.f;
#pragma unroll
        for (int r = 0; r < 17; ++r) {
            float e = __expf(lg[r] - m);
            ssum += e;
            esum += e * (float)r;
        }
        const float dist = esum * __builtin_amdgcn_rcpf(ssum) * (float)STRIDE;
        const int py = p / W, px = p % W;
        const float base = (q & 1) ? (float)(py * STRIDE) : (float)(px * STRIDE);
        const float val  = (q < 2) ? (base - dist) : (base + dist);
        out_box[((size_t)n * A_TOTAL + A_OFFp + p) * 4 + q] = val;
    }
}

extern "C" void kernel_launch(void* const* d_in, const int* in_sizes, int n_in,
                              void* d_out, int out_size, void* d_ws, size_t ws_size,
                              hipStream_t stream) {
    const float* x0  = (const float*)d_in[0];
    const float* x1  = (const float*)d_in[1];
    const float* x2  = (const float*)d_in[2];
    const float* wc0 = (const float*)d_in[3];
    const float* bc0 = (const float*)d_in[4];
    const float* wr0 = (const float*)d_in[5];
    const float* br0 = (const float*)d_in[6];
    const float* wc1 = (const float*)d_in[7];
    const float* bc1 = (const float*)d_in[8];
    const float* wr1 = (const float*)d_in[9];
    const float* br1 = (const float*)d_in[10];
    const float* wc2 = (const float*)d_in[11];
    const float* bc2 = (const float*)d_in[12];
    const float* wr2 = (const float*)d_in[13];
    const float* br2 = (const float*)d_in[14];
    const float* scl = (const float*)d_in[15];

    float* out_cls = (float*)d_out;
    float* out_box = (float*)d_out + (size_t)BATCH * A_TOTAL * NCLS;

    __hip_bfloat16* af  = (__hip_bfloat16*)d_ws;
    __hip_bfloat16* af0 = af;
    __hip_bfloat16* af1 = af + 184320;
    __hip_bfloat16* af2 = af + 552960;
    __hip_bfloat16* xT  = af + 1290240;   // padded image region, reused per level
    float* pbuf = (float*)((char*)xT + 15859712);

    prep_w_all<<<dim3(630), 256, 0, stream>>>(wc0, wr0, wc1, wr1, wc2, wr2,
                                              af0, af1, af2);

    // L0: row-aligned tile NT=160 (2 rows), NF=5, WEU=2, shifted-ds_read taps
    transpose_x<128, 80, 80><<<dim3(32 * 80 * 2), 256, 0, stream>>>(x0, xT);
    gemm_head<128, 80, 80, 8, 0, 0, 160, 1, 256, 2, 1><<<dim3(32 * 40), 256, 0, stream>>>(
        xT, af0, bc0, br0, scl, out_cls, out_box, nullptr);

    // L1: 512-thr NT=128 (NF=2) WEU=4 (R10 best: 416 blocks, one-round fill)
    transpose_x<256, 40, 40><<<dim3(32 * 40 * 4), 256, 0, stream>>>(x1, xT);
    gemm_head<256, 40, 40, 16, 6400, 1, 128, 1, 512, 4, 0><<<dim3(32 * 13), 512, 0, stream>>>(
        xT, af1, bc1, br1, scl, out_cls, out_box, nullptr);

    // L2: NT=64, split-K KS=4, 256-thr, WEU=4 (NF=2 fits) -> 896 blocks
    transpose_x<512, 20, 20><<<dim3(32 * 20 * 8), 256, 0, stream>>>(x2, xT);
    gemm_head<512, 20, 20, 32, 8000, 2, 64, 4, 256, 4, 0><<<dim3(32 * 7 * 4), 256, 0, stream>>>(
        xT, af2, bc2, br2, scl, out_cls, out_box, pbuf);
    reduce_epi<20, 20, 32, 8000, 2, 7, 4><<<dim3(32 * 7), 256, 0, stream>>>(
        pbuf, bc2, br2, scl, out_cls, out_box);
}

// Round 23
// 226.597 us; speedup vs baseline: 1.1009x; 1.0558x over previous
//
#include <hip/hip_runtime.h>
#include <hip/hip_bf16.h>
#include <math.h>

#define BATCH   32
#define A_TOTAL 8400
#define NCLS    80

typedef __attribute__((ext_vector_type(8))) short bf16x8;
typedef __attribute__((ext_vector_type(4))) float f32x4;

__device__ __forceinline__ short f2bf(float f) {
    union { float f; unsigned u; } v; v.f = f;
    unsigned u = v.u + 0x7fffu + ((v.u >> 16) & 1u);   // round-nearest-even
    return (short)(u >> 16);
}

// fast sigmoid: v_exp_f32 + v_rcp_f32 (error ~2^-21, way under bf16-conv noise)
__device__ __forceinline__ float fsig(float x) {
    return __builtin_amdgcn_rcpf(1.f + __expf(-x));
}

// async global->LDS, 16B per lane; lds dest = wave-uniform base + lane*16
__device__ __forceinline__ void stage16(const void* g, void* ldsp) {
    __builtin_amdgcn_global_load_lds(
        (const __attribute__((address_space(1))) unsigned int*)g,
        (__attribute__((address_space(3))) unsigned int*)ldsp, 16, 0, 0);
}

// ---------------------------------------------------------------------------
// Weight prep body: Afrag[tap][kc][mf(10)][lane(64)][8] bf16, M pad 148->160.
// ---------------------------------------------------------------------------
__device__ __forceinline__ void prep_w_body(const float* wc, const float* wr,
                                            __hip_bfloat16* af, int C, int bidl) {
    const int KC = C / 32;
    const int total = 9 * KC * 10 * 64;
    int idx = bidl * 256 + threadIdx.x;
    if (idx >= total) return;
    int l   = idx & 63;
    int rem = idx >> 6;
    int mf  = rem % 10;
    int kc  = (rem / 10) % KC;
    int tap = rem / (10 * KC);
    int m     = mf * 16 + (l & 15);
    int cbase = kc * 32 + (l >> 4) * 8;
    short v[8];
#pragma unroll
    for (int j = 0; j < 8; ++j) {
        int c = cbase + j;
        float w = 0.f;
        if (m < 80)        w = wc[((size_t)m * C + c) * 9 + tap];
        else if (m < 148)  w = wr[((size_t)(m - 80) * C + c) * 9 + tap];
        v[j] = f2bf(w);
    }
    *(bf16x8*)((short*)af + (size_t)idx * 8) = *(bf16x8*)v;
}

// ---------------------------------------------------------------------------
// Transpose body: NCHW fp32 -> zero-padded xT[n][kc][j(4)][(H+2)(W+2)][8 bf16]
// ---------------------------------------------------------------------------
template<int C, int H, int W>
__device__ __forceinline__ void transpose_body(const float* __restrict__ x,
                                               __hip_bfloat16* __restrict__ xT,
                                               int b) {
    const int CC  = C / 64;
    const int KC  = C / 32;
    const int PW  = W + 2;
    const int PHW = (H + 2) * PW;
    int cch = b % CC;
    int y   = (b / CC) % H;
    int n   = b / (CC * H);
    __shared__ float sm[64][W + 1];
    const float* src = x + (((size_t)n * C + cch * 64) * H + y) * W;
    for (int i = threadIdx.x; i < 64 * (W / 4); i += 256) {
        int c = i / (W / 4), f4 = i % (W / 4);
        float4 v = *(const float4*)(src + (size_t)c * H * W + f4 * 4);
        sm[c][f4 * 4 + 0] = v.x;
        sm[c][f4 * 4 + 1] = v.y;
        sm[c][f4 * 4 + 2] = v.z;
        sm[c][f4 * 4 + 3] = v.w;
    }
    __syncthreads();
    short* base = (short*)xT + (size_t)n * KC * 4 * PHW * 8;
    for (int u = threadIdx.x; u < W * 8; u += 256) {
        int g8 = u / W, xc = u % W;
        int kc = cch * 2 + (g8 >> 2);
        int j  = g8 & 3;
        short v[8];
#pragma unroll
        for (int jj = 0; jj < 8; ++jj) v[jj] = f2bf(sm[g8 * 8 + jj][xc]);
        *(bf16x8*)(base + (((size_t)(kc * 4 + j)) * PHW + (y + 1) * PW + xc + 1) * 8) =
            *(bf16x8*)v;
    }
    bf16x8 z = (bf16x8)(short)0;
    if (threadIdx.x < 16) {
        int g8 = threadIdx.x >> 1, side = threadIdx.x & 1;
        int kc = cch * 2 + (g8 >> 2), j = g8 & 3;
        *(bf16x8*)(base + (((size_t)(kc * 4 + j)) * PHW + (y + 1) * PW + side * (W + 1)) * 8) = z;
    }
    if (y == 0) {
        for (int u = threadIdx.x; u < PW * 8; u += 256) {
            int g8 = u / PW, col = u % PW;
            int kc = cch * 2 + (g8 >> 2), j = g8 & 3;
            *(bf16x8*)(base + (((size_t)(kc * 4 + j)) * PHW + col) * 8) = z;
        }
    }
    if (y == H - 1) {
        for (int u = threadIdx.x; u < PW * 8; u += 256) {
            int g8 = u / PW, col = u % PW;
            int kc = cch * 2 + (g8 >> 2), j = g8 & 3;
            *(bf16x8*)(base + (((size_t)(kc * 4 + j)) * PHW + (H + 1) * PW + col) * 8) = z;
        }
    }
}

template<int C, int H, int W>
__global__ __launch_bounds__(256) void transpose_x(const float* __restrict__ x,
                                                   __hip_bfloat16* __restrict__ xT) {
    transpose_body<C, H, W>(x, xT, blockIdx.x);
}

// Fused: weight prep (blocks 0..629) + L0 transpose (blocks 630..5749).
// Independent writes (af vs xT); removes one dispatch drain.
__global__ __launch_bounds__(256) void prep_and_t0(
    const float* __restrict__ wc0, const float* __restrict__ wr0,
    const float* __restrict__ wc1, const float* __restrict__ wr1,
    const float* __restrict__ wc2, const float* __restrict__ wr2,
    __hip_bfloat16* __restrict__ af0, __hip_bfloat16* __restrict__ af1,
    __hip_bfloat16* __restrict__ af2,
    const float* __restrict__ x0, __hip_bfloat16* __restrict__ xT) {
    int b = blockIdx.x;
    if (b < 90)        prep_w_body(wc0, wr0, af0, 128, b);
    else if (b < 270)  prep_w_body(wc1, wr1, af1, 256, b - 90);
    else if (b < 630)  prep_w_body(wc2, wr2, af2, 512, b - 270);
    else               transpose_body<128, 80, 80>(x0, xT, b - 630);
}

// ---------------------------------------------------------------------------
// Implicit-GEMM head on zero-padded image.
// DPPB==0: flat-window LDS B, 9 taps, per-tap ds_reads (L1/L2 path).
// DPPB==1 (L0): row-aligned NT=160 tile (2 image rows, ng=row, NF=5, WEU=2).
//   B staged as 4 padded rows; per (dy,dx) tap the 5 B-frags are DIRECT
//   ds_reads at +-16B shifted offsets (no DPP chain on the LDS->MFMA path).
// A depth-1 register prefetch (depth 2 spills at every WEU — R13/R14/R20).
// ---------------------------------------------------------------------------
template<int C, int H, int W, int STRIDE, int A_OFFp, int LVL, int NT, int KS,
         int NTHR, int WEU, int DPPB>
__global__ __launch_bounds__(NTHR, WEU) void gemm_head(
    const __hip_bfloat16* __restrict__ xT,
    const __hip_bfloat16* __restrict__ af,
    const float* __restrict__ bc, const float* __restrict__ br,
    const float* __restrict__ scales,
    float* __restrict__ out_cls, float* __restrict__ out_box,
    float* __restrict__ pbuf) {
    constexpr int HW     = H * W;
    constexpr int PW     = W + 2;
    constexpr int PHW    = (H + 2) * PW;
    constexpr int WAVES  = NTHR / 64;
    constexpr int WN     = WAVES / 2;
    constexpr int NF     = NT / (16 * WN);
    static_assert(NT == WN * NF * 16, "NT must equal WN*NF*16");
    static_assert(!DPPB || (NF == 5 && W == 80 && NT == 160 && NTHR == 256 && KS == 1),
                  "row path assumes 2-row 160px tile");
    constexpr int TILES  = (HW + NT - 1) / NT;
    constexpr int KC     = C / 32;
    constexpr int KCS    = KC / KS;
    constexpr int DYMAX  = (NT - 1) / W + 1;
    constexpr int NSTAGE = NT + 2 * DYMAX + 2 * W + 7;
    constexpr int NS16   = NSTAGE * 16;
    constexpr int NG     = NSTAGE * 4;
    constexpr int ITBv   = DPPB ? 9 : ((NG + NTHR - 1) / NTHR);
    constexpr int BSZ    = DPPB ? (9 * NTHR * 16) : (ITBv * NTHR * 16);
    constexpr int EPI    = 68 * (NT + 4) * 4;
    constexpr int LDSB   = (KS > 1) ? (2 * BSZ) : ((2 * BSZ) > EPI ? (2 * BSZ) : EPI);
    static_assert(ITBv <= 9, "B staging spread exceeds tap steps");

    __shared__ __align__(16) char lds[LDSB];

    constexpr int NWG = BATCH * TILES * KS;
    const int bid  = blockIdx.x;
    const int swz  = (bid & 7) * (NWG / 8) + (bid >> 3);
    const int ks   = swz % KS;
    const int rest = swz / KS;
    const int tile = rest % TILES;
    const int n    = rest / TILES;

    const int tid   = threadIdx.x;
    const int l     = tid & 63;
    const int wid   = __builtin_amdgcn_readfirstlane(tid >> 6);
    const int mhalf = wid & 1;
    const int ng    = wid >> 1;      // n-group (DPPB: output image row within tile)
    const int lr    = l & 15;
    const int kg    = l >> 4;

    const char* xb  = (const char*)xT + (size_t)n * KC * 4 * PHW * 16;
    const char* afc = (const char*)af;

    const int p0    = tile * NT;

    int blane[NF];
    unsigned bsoff[ITBv];
    int base2 = 0;
    if constexpr (DPPB) {
        base2 = (kg * 515 + lr + 1) * 16;
#pragma unroll
        for (int it = 0; it < ITBv; ++it) {
            int idx = it * NTHR + tid; if (idx > 2059) idx = 2059;
            int j = idx / 515;
            int rem = idx - j * 515; if (rem > 511) rem = 511;
            int g = rem >> 7, px = rem & 127;
            int pos = px - 16; pos = pos < 0 ? 0 : (pos > W + 1 ? W + 1 : pos);
            int q = (2 * tile + g) * PW + pos;
            bsoff[it] = (unsigned)((j * PHW + q) * 16);
        }
    } else {
        const int qbase = (p0 / W) * PW + (p0 % W);
#pragma unroll
        for (int nf = 0; nf < NF; ++nf) {
            int p  = p0 + (ng * NF + nf) * 16 + lr;
            int qc = (p / W + 1) * PW + (p % W) + 1;
            blane[nf] = kg * NS16 + (qc - (W + 3) - qbase) * 16;
        }
#pragma unroll
        for (int it = 0; it < ITBv; ++it) {
            int idx = it * NTHR + tid;
            int j = idx / NSTAGE; if (j > 3) j = 3;
            int q = qbase + (idx - j * NSTAGE);
            if (q > PHW - 1) q = PHW - 1;
            if (q < 0) q = 0;
            bsoff[it] = (unsigned)((j * PHW + q) * 16);
        }
    }

    f32x4 acc[5][NF];
#pragma unroll
    for (int mf = 0; mf < 5; ++mf)
#pragma unroll
        for (int nf = 0; nf < NF; ++nf) acc[mf][nf] = (f32x4)0.f;

    auto stageB = [&](int it, int kc, unsigned dstbase) {
        stage16(xb + (size_t)kc * (4 * PHW * 16) + bsoff[it],
                &lds[dstbase + it * (NTHR * 16) + wid * 1024]);
    };
    auto loadA = [&](bf16x8* dst, int step) {
        const char* asrc = afc + (size_t)step * 10240 + mhalf * 5120 + l * 16;
#pragma unroll
        for (int mf = 0; mf < 5; ++mf)
            dst[mf] = *(const bf16x8*)(asrc + mf * 1024);
    };

    const int kc0 = ks * KCS;

    unsigned curB = 0;

    if constexpr (DPPB) {
        bf16x8 acur[5], anxt[5];
        loadA(acur, kc0);          // (tap0, kc0)
#pragma unroll
        for (int it = 0; it < ITBv; ++it) stageB(it, kc0, 0);
        __syncthreads();

#pragma unroll 1
        for (int kk = 0; kk < KCS; ++kk) {
            const int kc = kc0 + kk;
#pragma unroll
            for (int dy = 0; dy < 3; ++dy) {
                if (kk + 1 < KCS) {
#pragma unroll
                    for (int it = dy * 3; it < dy * 3 + 3; ++it)
                        stageB(it, kc + 1, BSZ - curB);
                }
                const int dyi = curB + base2 + (ng + dy) * 2048;
#pragma unroll
                for (int dx = 0; dx < 3; ++dx) {
                    const int tap = dy * 3 + dx;
                    const int nstep = (tap == 8) ? (kc + 1) : ((tap + 1) * KC + kc);
                    loadA(anxt, nstep);
                    const int off = dyi + (dx - 1) * 16;
                    bf16x8 b0 = *(const bf16x8*)&lds[off + 256];
                    bf16x8 b1 = *(const bf16x8*)&lds[off + 512];
                    bf16x8 b2 = *(const bf16x8*)&lds[off + 768];
                    bf16x8 b3 = *(const bf16x8*)&lds[off + 1024];
                    bf16x8 b4 = *(const bf16x8*)&lds[off + 1280];
                    bf16x8 bv[5] = {b0, b1, b2, b3, b4};
                    __builtin_amdgcn_s_setprio(1);
#pragma unroll
                    for (int nf = 0; nf < 5; ++nf)
#pragma unroll
                        for (int mf = 0; mf < 5; ++mf)
                            acc[mf][nf] = __builtin_amdgcn_mfma_f32_16x16x32_bf16(
                                acur[mf], bv[nf], acc[mf][nf], 0, 0, 0);
                    __builtin_amdgcn_s_setprio(0);
#pragma unroll
                    for (int mf = 0; mf < 5; ++mf) acur[mf] = anxt[mf];
                }
            }
            __syncthreads();
            curB = BSZ - curB;
        }
    } else {
        bf16x8 acur[5], anxt[5];
        loadA(acur, kc0);
#pragma unroll
        for (int it = 0; it < ITBv; ++it) stageB(it, kc0, 0);
        __syncthreads();
#pragma unroll 1
        for (int kk = 0; kk < KCS; ++kk) {
            const int kc = kc0 + kk;
#pragma unroll
            for (int tap = 0; tap < 9; ++tap) {
                if (tap < ITBv && kk + 1 < KCS)
                    stageB(tap, kc + 1, curB ^ BSZ);
                const int nstep = (tap == 8) ? (kc + 1) : ((tap + 1) * KC + kc);
                loadA(anxt, nstep);
                const int imm = ((tap / 3) * PW + (tap % 3)) * 16;
                __builtin_amdgcn_s_setprio(1);
#pragma unroll
                for (int nf = 0; nf < NF; ++nf) {
                    bf16x8 b = *(const bf16x8*)&lds[curB + blane[nf] + imm];
#pragma unroll
                    for (int mf = 0; mf < 5; ++mf)
                        acc[mf][nf] = __builtin_amdgcn_mfma_f32_16x16x32_bf16(
                            acur[mf], b, acc[mf][nf], 0, 0, 0);
                }
                __builtin_amdgcn_s_setprio(0);
#pragma unroll
                for (int mf = 0; mf < 5; ++mf) acur[mf] = anxt[mf];
            }
            __syncthreads();
            curB ^= BSZ;
        }
    }

    if constexpr (KS > 1) {
        float* pb = pbuf + (size_t)((n * TILES + tile) * KS + ks) * (160 * NT);
#pragma unroll
        for (int mf = 0; mf < 5; ++mf)
#pragma unroll
            for (int nf = 0; nf < NF; ++nf) {
                int col = (ng * NF + nf) * 16 + lr;
#pragma unroll
                for (int r = 0; r < 4; ++r) {
                    int ch = mhalf * 80 + mf * 16 + kg * 4 + r;
                    pb[ch * NT + col] = acc[mf][nf][r];
                }
            }
        return;
    } else {
        const float sc = scales[LVL];
        float* smf = (float*)lds;

        if (mhalf == 0) {
            float4 bias[5];
#pragma unroll
            for (int mf = 0; mf < 5; ++mf)
                bias[mf] = *(const float4*)(bc + mf * 16 + kg * 4);
#pragma unroll
            for (int nf = 0; nf < NF; ++nf) {
                int p = p0 + (ng * NF + nf) * 16 + lr;
                if (p < HW) {
                    float* oc = out_cls + ((size_t)n * A_TOTAL + A_OFFp + p) * NCLS;
#pragma unroll
                    for (int mf = 0; mf < 5; ++mf) {
                        f32x4 v = acc[mf][nf];
                        float4 s;
                        s.x = fsig(v[0] + bias[mf].x);
                        s.y = fsig(v[1] + bias[mf].y);
                        s.z = fsig(v[2] + bias[mf].z);
                        s.w = fsig(v[3] + bias[mf].w);
                        *(float4*)(oc + mf * 16 + kg * 4) = s;
                    }
                }
            }
        } else {
#pragma unroll
            for (int mf = 0; mf < 5; ++mf)
#pragma unroll
                for (int nf = 0; nf < NF; ++nf) {
                    int lpx = (ng * NF + nf) * 16 + lr;
#pragma unroll
                    for (int r = 0; r < 4; ++r) {
                        int ch = mf * 16 + kg * 4 + r;
                        if (ch < 68) smf[ch * (NT + 4) + lpx] = acc[mf][nf][r];
                    }
                }
        }
        __syncthreads();

        for (int u = tid; u < 4 * NT; u += NTHR) {
            int f   = u / NT;
            int lpx = u % NT;
            int p   = p0 + lpx;
            if (p < HW) {
                float lg[17];
                float m = -1e30f;
#pragma unroll
                for (int r = 0; r < 17; ++r) {
                    lg[r] = (smf[(f * 17 + r) * (NT + 4) + lpx] + br[f * 17 + r]) * sc;
                    m = fmaxf(m, lg[r]);
                }
                float ssum = 0.f, esum = 0.f;
#pragma unroll
                for (int r = 0; r < 17; ++r) {
                    float e = __expf(lg[r] - m);
                    ssum += e;
                    esum += e * (float)r;
                }
                const float dist = esum * __builtin_amdgcn_rcpf(ssum) * (float)STRIDE;
                const int py = p / W, px = p % W;
                const float base = (f & 1) ? (float)(py * STRIDE) : (float)(px * STRIDE);
                const float val  = (f < 2) ? (base - dist) : (base + dist);
                out_box[((size_t)n * A_TOTAL + A_OFFp + p) * 4 + f] = val;
            }
        }
    }
}

// ---------------------------------------------------------------------------
// Split-K reduce + epilogue (NT=64 tiles), fast exp.
// ---------------------------------------------------------------------------
template<int H, int W, int STRIDE, int A_OFFp, int LVL, int TILES, int KS>
__global__ __launch_bounds__(256) void reduce_epi(
    const float* __restrict__ pbuf,
    const float* __restrict__ bc, const float* __restrict__ br,
    const float* __restrict__ scales,
    float* __restrict__ out_cls, float* __restrict__ out_box) {
    constexpr int HW = H * W;
    const int bid  = blockIdx.x;
    const int tile = bid % TILES;
    const int n    = bid / TILES;
    const int tid  = threadIdx.x;
    const float* pb = pbuf + (size_t)(n * TILES + tile) * KS * 10240;

    __shared__ float smf[160 * 66];
    for (int idx = tid; idx < 160 * 64; idx += 256) {
        float s = 0.f;
#pragma unroll
        for (int k = 0; k < KS; ++k) s += pb[k * 10240 + idx];
        smf[(idx >> 6) * 66 + (idx & 63)] = s;
    }
    __syncthreads();

    const int q = tid >> 6;
    const int t = tid & 63;
    const int p = tile * 64 + t;
    if (p < HW) {
        float* oc = out_cls + ((size_t)n * A_TOTAL + A_OFFp + p) * NCLS + q * 20;
#pragma unroll
        for (int k = 0; k < 20; k += 4) {
            float4 v;
            v.x = fsig(smf[(q * 20 + k + 0) * 66 + t] + bc[q * 20 + k + 0]);
            v.y = fsig(smf[(q * 20 + k + 1) * 66 + t] + bc[q * 20 + k + 1]);
            v.z = fsig(smf[(q * 20 + k + 2) * 66 + t] + bc[q * 20 + k + 2]);
            v.w = fsig(smf[(q * 20 + k + 3) * 66 + t] + bc[q * 20 + k + 3]);
            *(float4*)(oc + k) = v;
        }
        const float sc = scales[LVL];
        float lg[17];
        float m = -1e30f;
#pragma unroll
        for (int r = 0; r < 17; ++r) {
            lg[r] = (smf[(80 + q * 17 + r) * 66 + t] + br[q * 17 + r]) * sc;
            m = fmaxf(m, lg[r]);
        }
        float ssum = 0.f, esum = 0.f;
#pragma unroll
        for (int r = 0; r < 17; ++r) {
            float e = __expf(lg[r] - m);
            ssum += e;
            esum += e * (float)r;
        }
        const float dist = esum * __builtin_amdgcn_rcpf(ssum) * (float)STRIDE;
        const int py = p / W, px = p % W;
        const float base = (q & 1) ? (float)(py * STRIDE) : (float)(px * STRIDE);
        const float val  = (q < 2) ? (base - dist) : (base + dist);
        out_box[((size_t)n * A_TOTAL + A_OFFp + p) * 4 + q] = val;
    }
}

extern "C" void kernel_launch(void* const* d_in, const int* in_sizes, int n_in,
                              void* d_out, int out_size, void* d_ws, size_t ws_size,
                              hipStream_t stream) {
    const float* x0  = (const float*)d_in[0];
    const float* x1  = (const float*)d_in[1];
    const float* x2  = (const float*)d_in[2];
    const float* wc0 = (const float*)d_in[3];
    const float* bc0 = (const float*)d_in[4];
    const float* wr0 = (const float*)d_in[5];
    const float* br0 = (const float*)d_in[6];
    const float* wc1 = (const float*)d_in[7];
    const float* bc1 = (const float*)d_in[8];
    const float* wr1 = (const float*)d_in[9];
    const float* br1 = (const float*)d_in[10];
    const float* wc2 = (const float*)d_in[11];
    const float* bc2 = (const float*)d_in[12];
    const float* wr2 = (const float*)d_in[13];
    const float* br2 = (const float*)d_in[14];
    const float* scl = (const float*)d_in[15];

    float* out_cls = (float*)d_out;
    float* out_box = (float*)d_out + (size_t)BATCH * A_TOTAL * NCLS;

    __hip_bfloat16* af  = (__hip_bfloat16*)d_ws;
    __hip_bfloat16* af0 = af;
    __hip_bfloat16* af1 = af + 184320;
    __hip_bfloat16* af2 = af + 552960;
    __hip_bfloat16* xT  = af + 1290240;   // padded image region, reused per level
    float* pbuf = (float*)((char*)xT + 15859712);

    // prep (all weights) + L0 transpose fused: one launch, one drain
    prep_and_t0<<<dim3(630 + 32 * 80 * 2), 256, 0, stream>>>(
        wc0, wr0, wc1, wr1, wc2, wr2, af0, af1, af2, x0, xT);

    // L0: row-aligned tile NT=160 (2 rows), NF=5, WEU=2, shifted-ds_read taps
    gemm_head<128, 80, 80, 8, 0, 0, 160, 1, 256, 2, 1><<<dim3(32 * 40), 256, 0, stream>>>(
        xT, af0, bc0, br0, scl, out_cls, out_box, nullptr);

    // L1: 512-thr NT=256 (WN=4, NF=4), WEU=2 -> 224 blocks, 1 block/CU,
    //     87.5% single-round fill; 4 MFMAs per A-load (2x R10's NF=2)
    transpose_x<256, 40, 40><<<dim3(32 * 40 * 4), 256, 0, stream>>>(x1, xT);
    gemm_head<256, 40, 40, 16, 6400, 1, 256, 1, 512, 2, 0><<<dim3(32 * 7), 512, 0, stream>>>(
        xT, af1, bc1, br1, scl, out_cls, out_box, nullptr);

    // L2: NT=64, split-K KS=4, 256-thr, WEU=4 (NF=2 fits) -> 896 blocks
    transpose_x<512, 20, 20><<<dim3(32 * 20 * 8), 256, 0, stream>>>(x2, xT);
    gemm_head<512, 20, 20, 32, 8000, 2, 64, 4, 256, 4, 0><<<dim3(32 * 7 * 4), 256, 0, stream>>>(
        xT, af2, bc2, br2, scl, out_cls, out_box, pbuf);
    reduce_epi<20, 20, 32, 8000, 2, 7, 4><<<dim3(32 * 7), 256, 0, stream>>>(
        pbuf, bc2, br2, scl, out_cls, out_box);
}

// Round 24
// 226.397 us; speedup vs baseline: 1.1019x; 1.0009x over previous
//
#include <hip/hip_runtime.h>
#include <hip/hip_bf16.h>
#include <math.h>

#define BATCH   32
#define A_TOTAL 8400
#define NCLS    80

typedef __attribute__((ext_vector_type(8))) short bf16x8;
typedef __attribute__((ext_vector_type(4))) float f32x4;

__device__ __forceinline__ short f2bf(float f) {
    union { float f; unsigned u; } v; v.f = f;
    unsigned u = v.u + 0x7fffu + ((v.u >> 16) & 1u);   // round-nearest-even
    return (short)(u >> 16);
}

// fast sigmoid: v_exp_f32 + v_rcp_f32 (error ~2^-21, way under bf16-conv noise)
__device__ __forceinline__ float fsig(float x) {
    return __builtin_amdgcn_rcpf(1.f + __expf(-x));
}

// async global->LDS, 16B per lane; lds dest = wave-uniform base + lane*16
__device__ __forceinline__ void stage16(const void* g, void* ldsp) {
    __builtin_amdgcn_global_load_lds(
        (const __attribute__((address_space(1))) unsigned int*)g,
        (__attribute__((address_space(3))) unsigned int*)ldsp, 16, 0, 0);
}

// ---------------------------------------------------------------------------
// Weight prep body: Afrag[tap][kc][mf(10)][lane(64)][8] bf16, M pad 148->160.
// ---------------------------------------------------------------------------
__device__ __forceinline__ void prep_w_body(const float* wc, const float* wr,
                                            __hip_bfloat16* af, int C, int bidl) {
    const int KC = C / 32;
    const int total = 9 * KC * 10 * 64;
    int idx = bidl * 256 + threadIdx.x;
    if (idx >= total) return;
    int l   = idx & 63;
    int rem = idx >> 6;
    int mf  = rem % 10;
    int kc  = (rem / 10) % KC;
    int tap = rem / (10 * KC);
    int m     = mf * 16 + (l & 15);
    int cbase = kc * 32 + (l >> 4) * 8;
    short v[8];
#pragma unroll
    for (int j = 0; j < 8; ++j) {
        int c = cbase + j;
        float w = 0.f;
        if (m < 80)        w = wc[((size_t)m * C + c) * 9 + tap];
        else if (m < 148)  w = wr[((size_t)(m - 80) * C + c) * 9 + tap];
        v[j] = f2bf(w);
    }
    *(bf16x8*)((short*)af + (size_t)idx * 8) = *(bf16x8*)v;
}

// ---------------------------------------------------------------------------
// Transpose body: NCHW fp32 -> zero-padded xT[n][kc][j(4)][(H+2)(W+2)][8 bf16]
// ---------------------------------------------------------------------------
template<int C, int H, int W>
__device__ __forceinline__ void transpose_body(const float* __restrict__ x,
                                               __hip_bfloat16* __restrict__ xT,
                                               int b) {
    const int CC  = C / 64;
    const int KC  = C / 32;
    const int PW  = W + 2;
    const int PHW = (H + 2) * PW;
    int cch = b % CC;
    int y   = (b / CC) % H;
    int n   = b / (CC * H);
    __shared__ float sm[64][W + 1];
    const float* src = x + (((size_t)n * C + cch * 64) * H + y) * W;
    for (int i = threadIdx.x; i < 64 * (W / 4); i += 256) {
        int c = i / (W / 4), f4 = i % (W / 4);
        float4 v = *(const float4*)(src + (size_t)c * H * W + f4 * 4);
        sm[c][f4 * 4 + 0] = v.x;
        sm[c][f4 * 4 + 1] = v.y;
        sm[c][f4 * 4 + 2] = v.z;
        sm[c][f4 * 4 + 3] = v.w;
    }
    __syncthreads();
    short* base = (short*)xT + (size_t)n * KC * 4 * PHW * 8;
    for (int u = threadIdx.x; u < W * 8; u += 256) {
        int g8 = u / W, xc = u % W;
        int kc = cch * 2 + (g8 >> 2);
        int j  = g8 & 3;
        short v[8];
#pragma unroll
        for (int jj = 0; jj < 8; ++jj) v[jj] = f2bf(sm[g8 * 8 + jj][xc]);
        *(bf16x8*)(base + (((size_t)(kc * 4 + j)) * PHW + (y + 1) * PW + xc + 1) * 8) =
            *(bf16x8*)v;
    }
    bf16x8 z = (bf16x8)(short)0;
    if (threadIdx.x < 16) {
        int g8 = threadIdx.x >> 1, side = threadIdx.x & 1;
        int kc = cch * 2 + (g8 >> 2), j = g8 & 3;
        *(bf16x8*)(base + (((size_t)(kc * 4 + j)) * PHW + (y + 1) * PW + side * (W + 1)) * 8) = z;
    }
    if (y == 0) {
        for (int u = threadIdx.x; u < PW * 8; u += 256) {
            int g8 = u / PW, col = u % PW;
            int kc = cch * 2 + (g8 >> 2), j = g8 & 3;
            *(bf16x8*)(base + (((size_t)(kc * 4 + j)) * PHW + col) * 8) = z;
        }
    }
    if (y == H - 1) {
        for (int u = threadIdx.x; u < PW * 8; u += 256) {
            int g8 = u / PW, col = u % PW;
            int kc = cch * 2 + (g8 >> 2), j = g8 & 3;
            *(bf16x8*)(base + (((size_t)(kc * 4 + j)) * PHW + (H + 1) * PW + col) * 8) = z;
        }
    }
}

template<int C, int H, int W>
__global__ __launch_bounds__(256) void transpose_x(const float* __restrict__ x,
                                                   __hip_bfloat16* __restrict__ xT) {
    transpose_body<C, H, W>(x, xT, blockIdx.x);
}

// Fused prologue: weight prep (0..629) + L0 transpose (630..5749) +
// L2 transpose into its own xT2 (5750..10869). All writes independent.
__global__ __launch_bounds__(256) void prep_t0_t2(
    const float* __restrict__ wc0, const float* __restrict__ wr0,
    const float* __restrict__ wc1, const float* __restrict__ wr1,
    const float* __restrict__ wc2, const float* __restrict__ wr2,
    __hip_bfloat16* __restrict__ af0, __hip_bfloat16* __restrict__ af1,
    __hip_bfloat16* __restrict__ af2,
    const float* __restrict__ x0, __hip_bfloat16* __restrict__ xT,
    const float* __restrict__ x2, __hip_bfloat16* __restrict__ xT2) {
    int b = blockIdx.x;
    if (b < 90)         prep_w_body(wc0, wr0, af0, 128, b);
    else if (b < 270)   prep_w_body(wc1, wr1, af1, 256, b - 90);
    else if (b < 630)   prep_w_body(wc2, wr2, af2, 512, b - 270);
    else if (b < 5750)  transpose_body<128, 80, 80>(x0, xT, b - 630);
    else                transpose_body<512, 20, 20>(x2, xT2, b - 5750);
}

// ---------------------------------------------------------------------------
// Implicit-GEMM head on zero-padded image.
// DPPB==0: flat-window LDS B, 9 taps, per-tap ds_reads (L1/L2 path).
// DPPB==1 (L0): row-aligned NT=160 tile (2 image rows, ng=row, NF=5, WEU=2).
//   B staged as 4 padded rows; per (dy,dx) tap the 5 B-frags are DIRECT
//   ds_reads at +-16B shifted offsets (no DPP chain on the LDS->MFMA path).
// A depth-1 register prefetch (depth 2 spills at every WEU — R13/R14/R20).
// ---------------------------------------------------------------------------
template<int C, int H, int W, int STRIDE, int A_OFFp, int LVL, int NT, int KS,
         int NTHR, int WEU, int DPPB>
__global__ __launch_bounds__(NTHR, WEU) void gemm_head(
    const __hip_bfloat16* __restrict__ xT,
    const __hip_bfloat16* __restrict__ af,
    const float* __restrict__ bc, const float* __restrict__ br,
    const float* __restrict__ scales,
    float* __restrict__ out_cls, float* __restrict__ out_box,
    float* __restrict__ pbuf) {
    constexpr int HW     = H * W;
    constexpr int PW     = W + 2;
    constexpr int PHW    = (H + 2) * PW;
    constexpr int WAVES  = NTHR / 64;
    constexpr int WN     = WAVES / 2;
    constexpr int NF     = NT / (16 * WN);
    static_assert(NT == WN * NF * 16, "NT must equal WN*NF*16");
    static_assert(!DPPB || (NF == 5 && W == 80 && NT == 160 && NTHR == 256 && KS == 1),
                  "row path assumes 2-row 160px tile");
    constexpr int TILES  = (HW + NT - 1) / NT;
    constexpr int KC     = C / 32;
    constexpr int KCS    = KC / KS;
    constexpr int DYMAX  = (NT - 1) / W + 1;
    constexpr int NSTAGE = NT + 2 * DYMAX + 2 * W + 7;
    constexpr int NS16   = NSTAGE * 16;
    constexpr int NG     = NSTAGE * 4;
    constexpr int ITBv   = DPPB ? 9 : ((NG + NTHR - 1) / NTHR);
    constexpr int BSZ    = DPPB ? (9 * NTHR * 16) : (ITBv * NTHR * 16);
    constexpr int EPI    = 68 * (NT + 4) * 4;
    constexpr int LDSB   = (KS > 1) ? (2 * BSZ) : ((2 * BSZ) > EPI ? (2 * BSZ) : EPI);
    static_assert(ITBv <= 9, "B staging spread exceeds tap steps");

    __shared__ __align__(16) char lds[LDSB];

    constexpr int NWG = BATCH * TILES * KS;
    const int bid  = blockIdx.x;
    const int swz  = (bid & 7) * (NWG / 8) + (bid >> 3);
    const int ks   = swz % KS;
    const int rest = swz / KS;
    const int tile = rest % TILES;
    const int n    = rest / TILES;

    const int tid   = threadIdx.x;
    const int l     = tid & 63;
    const int wid   = __builtin_amdgcn_readfirstlane(tid >> 6);
    const int mhalf = wid & 1;
    const int ng    = wid >> 1;      // n-group (DPPB: output image row within tile)
    const int lr    = l & 15;
    const int kg    = l >> 4;

    const char* xb  = (const char*)xT + (size_t)n * KC * 4 * PHW * 16;
    const char* afc = (const char*)af;

    const int p0    = tile * NT;

    int blane[NF];
    unsigned bsoff[ITBv];
    int base2 = 0;
    if constexpr (DPPB) {
        base2 = (kg * 515 + lr + 1) * 16;
#pragma unroll
        for (int it = 0; it < ITBv; ++it) {
            int idx = it * NTHR + tid; if (idx > 2059) idx = 2059;
            int j = idx / 515;
            int rem = idx - j * 515; if (rem > 511) rem = 511;
            int g = rem >> 7, px = rem & 127;
            int pos = px - 16; pos = pos < 0 ? 0 : (pos > W + 1 ? W + 1 : pos);
            int q = (2 * tile + g) * PW + pos;
            bsoff[it] = (unsigned)((j * PHW + q) * 16);
        }
    } else {
        const int qbase = (p0 / W) * PW + (p0 % W);
#pragma unroll
        for (int nf = 0; nf < NF; ++nf) {
            int p  = p0 + (ng * NF + nf) * 16 + lr;
            int qc = (p / W + 1) * PW + (p % W) + 1;
            blane[nf] = kg * NS16 + (qc - (W + 3) - qbase) * 16;
        }
#pragma unroll
        for (int it = 0; it < ITBv; ++it) {
            int idx = it * NTHR + tid;
            int j = idx / NSTAGE; if (j > 3) j = 3;
            int q = qbase + (idx - j * NSTAGE);
            if (q > PHW - 1) q = PHW - 1;
            if (q < 0) q = 0;
            bsoff[it] = (unsigned)((j * PHW + q) * 16);
        }
    }

    f32x4 acc[5][NF];
#pragma unroll
    for (int mf = 0; mf < 5; ++mf)
#pragma unroll
        for (int nf = 0; nf < NF; ++nf) acc[mf][nf] = (f32x4)0.f;

    auto stageB = [&](int it, int kc, unsigned dstbase) {
        stage16(xb + (size_t)kc * (4 * PHW * 16) + bsoff[it],
                &lds[dstbase + it * (NTHR * 16) + wid * 1024]);
    };
    auto loadA = [&](bf16x8* dst, int step) {
        const char* asrc = afc + (size_t)step * 10240 + mhalf * 5120 + l * 16;
#pragma unroll
        for (int mf = 0; mf < 5; ++mf)
            dst[mf] = *(const bf16x8*)(asrc + mf * 1024);
    };

    const int kc0 = ks * KCS;

    unsigned curB = 0;

    if constexpr (DPPB) {
        bf16x8 acur[5], anxt[5];
        loadA(acur, kc0);          // (tap0, kc0)
#pragma unroll
        for (int it = 0; it < ITBv; ++it) stageB(it, kc0, 0);
        __syncthreads();

#pragma unroll 1
        for (int kk = 0; kk < KCS; ++kk) {
            const int kc = kc0 + kk;
#pragma unroll
            for (int dy = 0; dy < 3; ++dy) {
                if (kk + 1 < KCS) {
#pragma unroll
                    for (int it = dy * 3; it < dy * 3 + 3; ++it)
                        stageB(it, kc + 1, BSZ - curB);
                }
                const int dyi = curB + base2 + (ng + dy) * 2048;
#pragma unroll
                for (int dx = 0; dx < 3; ++dx) {
                    const int tap = dy * 3 + dx;
                    const int nstep = (tap == 8) ? (kc + 1) : ((tap + 1) * KC + kc);
                    loadA(anxt, nstep);
                    const int off = dyi + (dx - 1) * 16;
                    bf16x8 b0 = *(const bf16x8*)&lds[off + 256];
                    bf16x8 b1 = *(const bf16x8*)&lds[off + 512];
                    bf16x8 b2 = *(const bf16x8*)&lds[off + 768];
                    bf16x8 b3 = *(const bf16x8*)&lds[off + 1024];
                    bf16x8 b4 = *(const bf16x8*)&lds[off + 1280];
                    bf16x8 bv[5] = {b0, b1, b2, b3, b4};
                    __builtin_amdgcn_s_setprio(1);
#pragma unroll
                    for (int nf = 0; nf < 5; ++nf)
#pragma unroll
                        for (int mf = 0; mf < 5; ++mf)
                            acc[mf][nf] = __builtin_amdgcn_mfma_f32_16x16x32_bf16(
                                acur[mf], bv[nf], acc[mf][nf], 0, 0, 0);
                    __builtin_amdgcn_s_setprio(0);
#pragma unroll
                    for (int mf = 0; mf < 5; ++mf) acur[mf] = anxt[mf];
                }
            }
            __syncthreads();
            curB = BSZ - curB;
        }
    } else {
        bf16x8 acur[5], anxt[5];
        loadA(acur, kc0);
#pragma unroll
        for (int it = 0; it < ITBv; ++it) stageB(it, kc0, 0);
        __syncthreads();
#pragma unroll 1
        for (int kk = 0; kk < KCS; ++kk) {
            const int kc = kc0 + kk;
#pragma unroll
            for (int tap = 0; tap < 9; ++tap) {
                if (tap < ITBv && kk + 1 < KCS)
                    stageB(tap, kc + 1, curB ^ BSZ);
                const int nstep = (tap == 8) ? (kc + 1) : ((tap + 1) * KC + kc);
                loadA(anxt, nstep);
                const int imm = ((tap / 3) * PW + (tap % 3)) * 16;
                __builtin_amdgcn_s_setprio(1);
#pragma unroll
                for (int nf = 0; nf < NF; ++nf) {
                    bf16x8 b = *(const bf16x8*)&lds[curB + blane[nf] + imm];
#pragma unroll
                    for (int mf = 0; mf < 5; ++mf)
                        acc[mf][nf] = __builtin_amdgcn_mfma_f32_16x16x32_bf16(
                            acur[mf], b, acc[mf][nf], 0, 0, 0);
                }
                __builtin_amdgcn_s_setprio(0);
#pragma unroll
                for (int mf = 0; mf < 5; ++mf) acur[mf] = anxt[mf];
            }
            __syncthreads();
            curB ^= BSZ;
        }
    }

    if constexpr (KS > 1) {
        float* pb = pbuf + (size_t)((n * TILES + tile) * KS + ks) * (160 * NT);
#pragma unroll
        for (int mf = 0; mf < 5; ++mf)
#pragma unroll
            for (int nf = 0; nf < NF; ++nf) {
                int col = (ng * NF + nf) * 16 + lr;
#pragma unroll
                for (int r = 0; r < 4; ++r) {
                    int ch = mhalf * 80 + mf * 16 + kg * 4 + r;
                    pb[ch * NT + col] = acc[mf][nf][r];
                }
            }
        return;
    } else {
        const float sc = scales[LVL];
        float* smf = (float*)lds;

        if (mhalf == 0) {
            float4 bias[5];
#pragma unroll
            for (int mf = 0; mf < 5; ++mf)
                bias[mf] = *(const float4*)(bc + mf * 16 + kg * 4);
#pragma unroll
            for (int nf = 0; nf < NF; ++nf) {
                int p = p0 + (ng * NF + nf) * 16 + lr;
                if (p < HW) {
                    float* oc = out_cls + ((size_t)n * A_TOTAL + A_OFFp + p) * NCLS;
#pragma unroll
                    for (int mf = 0; mf < 5; ++mf) {
                        f32x4 v = acc[mf][nf];
                        float4 s;
                        s.x = fsig(v[0] + bias[mf].x);
                        s.y = fsig(v[1] + bias[mf].y);
                        s.z = fsig(v[2] + bias[mf].z);
                        s.w = fsig(v[3] + bias[mf].w);
                        *(float4*)(oc + mf * 16 + kg * 4) = s;
                    }
                }
            }
        } else {
#pragma unroll
            for (int mf = 0; mf < 5; ++mf)
#pragma unroll
                for (int nf = 0; nf < NF; ++nf) {
                    int lpx = (ng * NF + nf) * 16 + lr;
#pragma unroll
                    for (int r = 0; r < 4; ++r) {
                        int ch = mf * 16 + kg * 4 + r;
                        if (ch < 68) smf[ch * (NT + 4) + lpx] = acc[mf][nf][r];
                    }
                }
        }
        __syncthreads();

        for (int u = tid; u < 4 * NT; u += NTHR) {
            int f   = u / NT;
            int lpx = u % NT;
            int p   = p0 + lpx;
            if (p < HW) {
                float lg[17];
                float m = -1e30f;
#pragma unroll
                for (int r = 0; r < 17; ++r) {
                    lg[r] = (smf[(f * 17 + r) * (NT + 4) + lpx] + br[f * 17 + r]) * sc;
                    m = fmaxf(m, lg[r]);
                }
                float ssum = 0.f, esum = 0.f;
#pragma unroll
                for (int r = 0; r < 17; ++r) {
                    float e = __expf(lg[r] - m);
                    ssum += e;
                    esum += e * (float)r;
                }
                const float dist = esum * __builtin_amdgcn_rcpf(ssum) * (float)STRIDE;
                const int py = p / W, px = p % W;
                const float base = (f & 1) ? (float)(py * STRIDE) : (float)(px * STRIDE);
                const float val  = (f < 2) ? (base - dist) : (base + dist);
                out_box[((size_t)n * A_TOTAL + A_OFFp + p) * 4 + f] = val;
            }
        }
    }
}

// ---------------------------------------------------------------------------
// Split-K reduce + epilogue (NT=64 tiles), fast exp.
// ---------------------------------------------------------------------------
template<int H, int W, int STRIDE, int A_OFFp, int LVL, int TILES, int KS>
__global__ __launch_bounds__(256) void reduce_epi(
    const float* __restrict__ pbuf,
    const float* __restrict__ bc, const float* __restrict__ br,
    const float* __restrict__ scales,
    float* __restrict__ out_cls, float* __restrict__ out_box) {
    constexpr int HW = H * W;
    const int bid  = blockIdx.x;
    const int tile = bid % TILES;
    const int n    = bid / TILES;
    const int tid  = threadIdx.x;
    const float* pb = pbuf + (size_t)(n * TILES + tile) * KS * 10240;

    __shared__ float smf[160 * 66];
    for (int idx = tid; idx < 160 * 64; idx += 256) {
        float s = 0.f;
#pragma unroll
        for (int k = 0; k < KS; ++k) s += pb[k * 10240 + idx];
        smf[(idx >> 6) * 66 + (idx & 63)] = s;
    }
    __syncthreads();

    const int q = tid >> 6;
    const int t = tid & 63;
    const int p = tile * 64 + t;
    if (p < HW) {
        float* oc = out_cls + ((size_t)n * A_TOTAL + A_OFFp + p) * NCLS + q * 20;
#pragma unroll
        for (int k = 0; k < 20; k += 4) {
            float4 v;
            v.x = fsig(smf[(q * 20 + k + 0) * 66 + t] + bc[q * 20 + k + 0]);
            v.y = fsig(smf[(q * 20 + k + 1) * 66 + t] + bc[q * 20 + k + 1]);
            v.z = fsig(smf[(q * 20 + k + 2) * 66 + t] + bc[q * 20 + k + 2]);
            v.w = fsig(smf[(q * 20 + k + 3) * 66 + t] + bc[q * 20 + k + 3]);
            *(float4*)(oc + k) = v;
        }
        const float sc = scales[LVL];
        float lg[17];
        float m = -1e30f;
#pragma unroll
        for (int r = 0; r < 17; ++r) {
            lg[r] = (smf[(80 + q * 17 + r) * 66 + t] + br[q * 17 + r]) * sc;
            m = fmaxf(m, lg[r]);
        }
        float ssum = 0.f, esum = 0.f;
#pragma unroll
        for (int r = 0; r < 17; ++r) {
            float e = __expf(lg[r] - m);
            ssum += e;
            esum += e * (float)r;
        }
        const float dist = esum * __builtin_amdgcn_rcpf(ssum) * (float)STRIDE;
        const int py = p / W, px = p % W;
        const float base = (q & 1) ? (float)(py * STRIDE) : (float)(px * STRIDE);
        const float val  = (q < 2) ? (base - dist) : (base + dist);
        out_box[((size_t)n * A_TOTAL + A_OFFp + p) * 4 + q] = val;
    }
}

extern "C" void kernel_launch(void* const* d_in, const int* in_sizes, int n_in,
                              void* d_out, int out_size, void* d_ws, size_t ws_size,
                              hipStream_t stream) {
    const float* x0  = (const float*)d_in[0];
    const float* x1  = (const float*)d_in[1];
    const float* x2  = (const float*)d_in[2];
    const float* wc0 = (const float*)d_in[3];
    const float* bc0 = (const float*)d_in[4];
    const float* wr0 = (const float*)d_in[5];
    const float* br0 = (const float*)d_in[6];
    const float* wc1 = (const float*)d_in[7];
    const float* bc1 = (const float*)d_in[8];
    const float* wr1 = (const float*)d_in[9];
    const float* br1 = (const float*)d_in[10];
    const float* wc2 = (const float*)d_in[11];
    const float* bc2 = (const float*)d_in[12];
    const float* wr2 = (const float*)d_in[13];
    const float* br2 = (const float*)d_in[14];
    const float* scl = (const float*)d_in[15];

    float* out_cls = (float*)d_out;
    float* out_box = (float*)d_out + (size_t)BATCH * A_TOTAL * NCLS;

    __hip_bfloat16* af  = (__hip_bfloat16*)d_ws;
    __hip_bfloat16* af0 = af;
    __hip_bfloat16* af1 = af + 184320;
    __hip_bfloat16* af2 = af + 552960;
    __hip_bfloat16* xT  = af + 1290240;              // L0/L1 padded image region
    float*          pbuf = (float*)((char*)xT + 15859712);   // inside xT footprint
    __hip_bfloat16* xT2 = (__hip_bfloat16*)((char*)xT + 55083008);  // L2's own region

    // Fused prologue: all weight prep + L0 transpose + L2 transpose (own buffer)
    prep_t0_t2<<<dim3(630 + 32 * 80 * 2 + 32 * 20 * 8), 256, 0, stream>>>(
        wc0, wr0, wc1, wr1, wc2, wr2, af0, af1, af2, x0, xT, x2, xT2);

    // L0: row-aligned tile NT=160 (2 rows), NF=5, WEU=2, shifted-ds_read taps
    gemm_head<128, 80, 80, 8, 0, 0, 160, 1, 256, 2, 1><<<dim3(32 * 40), 256, 0, stream>>>(
        xT, af0, bc0, br0, scl, out_cls, out_box, nullptr);

    // L1: 512-thr NT=256 (WN=4, NF=4), WEU=2 -> 224 blocks, 87.5% one-round fill
    transpose_x<256, 40, 40><<<dim3(32 * 40 * 4), 256, 0, stream>>>(x1, xT);
    gemm_head<256, 40, 40, 16, 6400, 1, 256, 1, 512, 2, 0><<<dim3(32 * 7), 512, 0, stream>>>(
        xT, af1, bc1, br1, scl, out_cls, out_box, nullptr);

    // L2: NT=64, split-K KS=4 (reads xT2; pbuf write ordered after L1 gemm)
    gemm_head<512, 20, 20, 32, 8000, 2, 64, 4, 256, 4, 0><<<dim3(32 * 7 * 4), 256, 0, stream>>>(
        xT2, af2, bc2, br2, scl, out_cls, out_box, pbuf);
    reduce_epi<20, 20, 32, 8000, 2, 7, 4><<<dim3(32 * 7), 256, 0, stream>>>(
        pbuf, bc2, br2, scl, out_cls, out_box);
}